// Round 3
// baseline (1018.913 us; speedup 1.0000x reference)
//
#include <hip/hip_runtime.h>
#include <math.h>

// ---------------------------------------------------------------------------
// Problem constants (B=8, N1=128, N2=256, D=128, L=3, NH=54)
// Packed row space: rows 0..1023 = ligand (b*128+i), rows 1024..3071 = target
// (1024 + b*256 + j).  All per-row linears run once over 3072 rows.
// ---------------------------------------------------------------------------
#define BB 8
#define N1C 128
#define N2C 256
#define DC 128
#define NHC 54
#define ROWS_L 1024
#define ROWS_T 2048
#define ROWS_ALL 3072

// ---------------------------------------------------------------------------
// Reductions (wave64)
// ---------------------------------------------------------------------------
__device__ __forceinline__ float wredSum(float v) {
#pragma unroll
  for (int o = 32; o > 0; o >>= 1) v += __shfl_down(v, o);
  return v;
}
__device__ float blockSum(float v) {
  __shared__ float red[9];
  v = wredSum(v);
  int lane = threadIdx.x & 63, wid = threadIdx.x >> 6;
  __syncthreads();
  if (lane == 0) red[wid] = v;
  __syncthreads();
  if (threadIdx.x == 0) {
    float s = 0.f;
    int nw = (blockDim.x + 63) >> 6;
    for (int i = 0; i < nw; ++i) s += red[i];
    red[8] = s;
  }
  __syncthreads();
  return red[8];
}

// ---------------------------------------------------------------------------
// Embedding: H0[r][d] = (r<1024 ? ligand_h[r] : target_h[r-1024]) @ emb_w
// ---------------------------------------------------------------------------
__global__ __launch_bounds__(128) void k_emb(const float* __restrict__ LH,
                                             const float* __restrict__ TH,
                                             const float* __restrict__ W,
                                             float* __restrict__ H0) {
  int r0 = blockIdx.x * 8;
  __shared__ float xs[8][NHC];
  for (int t = threadIdx.x; t < 8 * NHC; t += 128) {
    int rr = r0 + t / NHC, c = t % NHC;
    xs[t / NHC][c] = (rr < ROWS_L) ? LH[(long)rr * NHC + c]
                                   : TH[(long)(rr - ROWS_L) * NHC + c];
  }
  __syncthreads();
  int d = threadIdx.x;
  float acc[8];
#pragma unroll
  for (int r = 0; r < 8; ++r) acc[r] = 0.f;
  for (int k = 0; k < NHC; ++k) {
    float wv = W[(long)k * DC + d];
#pragma unroll
    for (int r = 0; r < 8; ++r) acc[r] += xs[r][k] * wv;
  }
#pragma unroll
  for (int r = 0; r < 8; ++r) H0[(long)(r0 + r) * DC + d] = acc[r];
}

// ---------------------------------------------------------------------------
// Fused GAT linears: NT = X@W + b ; E1 = NT@ATT.  8 rows/block.
// ---------------------------------------------------------------------------
__global__ __launch_bounds__(128) void k_nte1(const float* __restrict__ X,
                                              const float* __restrict__ W,
                                              const float* __restrict__ bias,
                                              const float* __restrict__ ATT,
                                              float* __restrict__ NT,
                                              float* __restrict__ E1) {
  int r0 = blockIdx.x * 8;
  __shared__ float xs[8][DC], nts[8][DC];
  for (int t = threadIdx.x; t < 8 * DC; t += 128)
    xs[t >> 7][t & 127] = X[(long)r0 * DC + t];
  __syncthreads();
  int d = threadIdx.x;
  float acc[8];
#pragma unroll
  for (int r = 0; r < 8; ++r) acc[r] = 0.f;
#pragma unroll 2
  for (int k = 0; k < DC; ++k) {
    float wv = W[(long)k * DC + d];
#pragma unroll
    for (int r = 0; r < 8; ++r) acc[r] += xs[r][k] * wv;
  }
  float bv = bias[d];
#pragma unroll
  for (int r = 0; r < 8; ++r) {
    float v = acc[r] + bv;
    nts[r][d] = v;
    NT[(long)(r0 + r) * DC + d] = v;
  }
  __syncthreads();
#pragma unroll
  for (int r = 0; r < 8; ++r) acc[r] = 0.f;
#pragma unroll 2
  for (int k = 0; k < DC; ++k) {
    float av = ATT[(long)k * DC + d];
#pragma unroll
    for (int r = 0; r < 8; ++r) acc[r] += nts[r][k] * av;
  }
#pragma unroll
  for (int r = 0; r < 8; ++r) E1[(long)(r0 + r) * DC + d] = acc[r];
}

// ---------------------------------------------------------------------------
// Fused GAT attention: per block = 16 rows of one batch.
//   logits[r][k] = e1_r.nt_k + nt_r.e1_k  (masked by adj, adj is binary with
//   guaranteed diagonal), softmax over k, OUT = relu(P @ NT).
// ---------------------------------------------------------------------------
template <int N>
__global__ __launch_bounds__(256) void k_attn(const float* __restrict__ NT,
                                              const float* __restrict__ E1,
                                              const float* __restrict__ ADJ,
                                              float* __restrict__ OUT,
                                              int baseRow) {
  __shared__ float e1r[16][DC + 4], ntr[16][DC + 4];
  __shared__ float col[32][DC + 4];
  __shared__ float aw[16][N + 4];
  int b = blockIdx.y;
  int r0 = blockIdx.x * 16;
  int rowBase = baseRow + b * N;
  int tid = threadIdx.x;
  int r = tid >> 4, ks = tid & 15;
  for (int t = tid; t < 16 * DC; t += 256) {
    int rr = t >> 7, d = t & 127;
    e1r[rr][d] = E1[(long)(rowBase + r0 + rr) * DC + d];
    ntr[rr][d] = NT[(long)(rowBase + r0 + rr) * DC + d];
  }
  const float* adjb = ADJ + (long)b * N * N;
  for (int k0 = 0; k0 < N; k0 += 32) {
    __syncthreads();
    for (int t = tid; t < 32 * DC; t += 256) {
      int kk = t >> 7, d = t & 127;
      col[kk][d] = NT[(long)(rowBase + k0 + kk) * DC + d];
    }
    __syncthreads();
    float a0 = 0.f, a1 = 0.f;
#pragma unroll 4
    for (int d = 0; d < DC; ++d) {
      float e = e1r[r][d];
      a0 += e * col[ks][d];
      a1 += e * col[ks + 16][d];
    }
    __syncthreads();
    for (int t = tid; t < 32 * DC; t += 256) {
      int kk = t >> 7, d = t & 127;
      col[kk][d] = E1[(long)(rowBase + k0 + kk) * DC + d];
    }
    __syncthreads();
#pragma unroll 4
    for (int d = 0; d < DC; ++d) {
      float nv = ntr[r][d];
      a0 += nv * col[ks][d];
      a1 += nv * col[ks + 16][d];
    }
    float ad0 = adjb[(long)(r0 + r) * N + k0 + ks];
    float ad1 = adjb[(long)(r0 + r) * N + k0 + ks + 16];
    aw[r][k0 + ks] = (ad0 > 1e-6f) ? a0 : -9e15f;
    aw[r][k0 + ks + 16] = (ad1 > 1e-6f) ? a1 : -9e15f;
  }
  __syncthreads();
  // softmax over row (16 lanes cooperate), keep P unnormalized + 1/sum.
  float m = -INFINITY;
  for (int k = ks; k < N; k += 16) m = fmaxf(m, aw[r][k]);
#pragma unroll
  for (int o = 8; o > 0; o >>= 1) m = fmaxf(m, __shfl_xor(m, o));
  float s = 0.f;
  for (int k = ks; k < N; k += 16) {
    float p = expf(aw[r][k] - m);
    aw[r][k] = p;
    s += p;
  }
#pragma unroll
  for (int o = 8; o > 0; o >>= 1) s += __shfl_xor(s, o);
  float inv = 1.f / s;
  // OUT = relu(P @ NT) / s
  float acc[8];
#pragma unroll
  for (int q = 0; q < 8; ++q) acc[q] = 0.f;
  for (int k0 = 0; k0 < N; k0 += 32) {
    __syncthreads();
    for (int t = tid; t < 32 * DC; t += 256) {
      int kk = t >> 7, d = t & 127;
      col[kk][d] = NT[(long)(rowBase + k0 + kk) * DC + d];
    }
    __syncthreads();
#pragma unroll 8
    for (int kk = 0; kk < 32; ++kk) {
      float p = aw[r][k0 + kk];
#pragma unroll
      for (int q = 0; q < 8; ++q) acc[q] += p * col[kk][ks + 16 * q];
    }
  }
#pragma unroll
  for (int q = 0; q < 8; ++q)
    OUT[(long)(rowBase + r0 + r) * DC + ks + 16 * q] = fmaxf(acc[q] * inv, 0.f);
}

// gated residual: y = g*x + (1-g)*out,  g = sigmoid([x,out].gw + gb)
__global__ void k_gate(const float* __restrict__ X, const float* __restrict__ OUT,
                       const float* __restrict__ GW, const float* __restrict__ GB,
                       float* __restrict__ Y) {
  const int D = DC;
  long r = blockIdx.x;
  int d = threadIdx.x;
  float x = X[r * D + d], o = OUT[r * D + d];
  float s = blockSum(x * GW[d] + o * GW[D + d]);
  float g = 1.f / (1.f + expf(-(s + GB[0])));
  Y[r * D + d] = g * x + (1.f - g) * o;
}

// adj12 from positions
__global__ void k_adj12(const float* __restrict__ LP, const float* __restrict__ TP,
                        float* __restrict__ AD) {
  long idx = (long)blockIdx.x * blockDim.x + threadIdx.x;
  if (idx >= (long)BB * N1C * N2C) return;
  int j = idx & (N2C - 1);
  long t = idx >> 8;
  int i = (int)(t & (N1C - 1));
  int b = (int)(t >> 7);
  float dx = LP[((long)b * N1C + i) * 3 + 0] - TP[((long)b * N2C + j) * 3 + 0];
  float dy = LP[((long)b * N1C + i) * 3 + 1] - TP[((long)b * N2C + j) * 3 + 1];
  float dz = LP[((long)b * N1C + i) * 3 + 2] - TP[((long)b * N2C + j) * 3 + 2];
  float d = sqrtf(dx * dx + dy * dy + dz * dz + 1e-10f);
  if (d < 0.5f) d = 1e10f;
  AD[idx] = (d <= 5.0f && d > 1e-3f) ? 1.f : 0.f;
}

// ---------------------------------------------------------------------------
// Merged msg kernel: z=0 ligand update (Ni=128,Nj=256), z=1 target update
// (Ni=256,Nj=128, transposed EV access).  msg = relu(t1 + max_j m2_j*ev_ij).
// ---------------------------------------------------------------------------
__global__ __launch_bounds__(256) void k_msg2z(const float* __restrict__ T1,
                                               const float* __restrict__ M2,
                                               const float* __restrict__ EV,
                                               float* __restrict__ MSG) {
  int z = blockIdx.z, b = blockIdx.y;
  int Ni = z ? N2C : N1C, Nj = z ? N1C : N2C;
  int t1off = z ? ROWS_L : 0, m2off = z ? 0 : ROWS_L;
  long ev_is = z ? 1L : (long)N2C, ev_js = z ? (long)N2C : 1L;
  int i0 = blockIdx.x * 8;
  if (i0 >= Ni) return;
  __shared__ float m2s[32][DC];
  __shared__ float evs[8][32];
  int d = threadIdx.x & 127, io = threadIdx.x >> 7;
  float acc[4];
#pragma unroll
  for (int q = 0; q < 4; ++q) acc[q] = -INFINITY;
  const float* M2b = M2 + (long)(m2off + b * Nj) * DC;
  const float* EVb = EV + (long)b * (N1C * N2C);
  for (int j0 = 0; j0 < Nj; j0 += 32) {
    __syncthreads();
    for (int t = threadIdx.x; t < 32 * DC; t += 256)
      m2s[t >> 7][t & 127] = M2b[(long)(j0 + (t >> 7)) * DC + (t & 127)];
    for (int t = threadIdx.x; t < 8 * 32; t += 256)
      evs[t >> 5][t & 31] =
          EVb[(long)(i0 + (t >> 5)) * ev_is + (long)(j0 + (t & 31)) * ev_js];
    __syncthreads();
#pragma unroll 8
    for (int jj = 0; jj < 32; ++jj) {
      float m2v = m2s[jj][d];
#pragma unroll
      for (int q = 0; q < 4; ++q)
        acc[q] = fmaxf(acc[q], m2v * evs[io + 2 * q][jj]);
    }
  }
#pragma unroll
  for (int q = 0; q < 4; ++q) {
    int i = i0 + io + 2 * q;
    long row = t1off + (long)b * Ni + i;
    MSG[row * DC + d] = fmaxf(T1[row * DC + d] + acc[q], 0.f);
  }
}

// ---------------------------------------------------------------------------
// Fused GRU over all 3072 rows: gi = msg@WihT+bih, gh = h@WhhT+bhh, combine.
// ---------------------------------------------------------------------------
__global__ __launch_bounds__(384) void k_gruf(
    const float* __restrict__ MSGp, const float* __restrict__ Hp,
    const float* __restrict__ WihT, const float* __restrict__ WhhT,
    const float* __restrict__ bih, const float* __restrict__ bhh,
    float* __restrict__ Y) {
  const int D = DC;
  int r0 = blockIdx.x * 8;
  __shared__ float xs[8][DC], hs[8][DC];
  __shared__ float gis[8][384], ghs[8][384];
  for (int t = threadIdx.x; t < 8 * DC; t += 384) {
    int r = t >> 7, c = t & 127;
    xs[r][c] = MSGp[(long)(r0 + r) * D + c];
    hs[r][c] = Hp[(long)(r0 + r) * D + c];
  }
  __syncthreads();
  int dd = threadIdx.x;
  float ai[8], ah[8];
#pragma unroll
  for (int r = 0; r < 8; ++r) { ai[r] = 0.f; ah[r] = 0.f; }
#pragma unroll 2
  for (int k = 0; k < DC; ++k) {
    float wi = WihT[(long)k * 384 + dd];
    float wh = WhhT[(long)k * 384 + dd];
#pragma unroll
    for (int r = 0; r < 8; ++r) {
      ai[r] += xs[r][k] * wi;
      ah[r] += hs[r][k] * wh;
    }
  }
  float bi = bih[dd], bh = bhh[dd];
#pragma unroll
  for (int r = 0; r < 8; ++r) {
    gis[r][dd] = ai[r] + bi;
    ghs[r][dd] = ah[r] + bh;
  }
  __syncthreads();
  for (int t = threadIdx.x; t < 8 * DC; t += 384) {
    int r = t >> 7, d = t & 127;
    float ir = gis[r][d], iz = gis[r][d + 128], inn = gis[r][d + 256];
    float hr = ghs[r][d], hz = ghs[r][d + 128], hn = ghs[r][d + 256];
    float rg = 1.f / (1.f + expf(-(ir + hr)));
    float zg = 1.f / (1.f + expf(-(iz + hz)));
    float ng = tanhf(inn + rg * hn);
    Y[(long)(r0 + r) * D + d] = (1.f - zg) * ng + zg * hs[r][d];
  }
}

// ---------------------------------------------------------------------------
// Dual-head linear: Y1 = X@W1(+b1), Y2 = X@W2(+b2).  K=Dout=128.
// trans=1 stores transposed per batch: Y[b][d][row_in_batch].
// ---------------------------------------------------------------------------
template <int RB>
__global__ __launch_bounds__(128) void k_feat2(
    const float* __restrict__ X, const float* __restrict__ W1,
    const float* __restrict__ b1, const float* __restrict__ W2,
    const float* __restrict__ b2, float* __restrict__ Y1, float* __restrict__ Y2,
    int rpb, int trans) {
  int r0 = blockIdx.x * RB;
  __shared__ float xs[RB][DC];
  for (int t = threadIdx.x; t < RB * DC; t += 128)
    xs[t >> 7][t & 127] = X[(long)(r0 + (t >> 7)) * DC + (t & 127)];
  __syncthreads();
  int d = threadIdx.x;
  float a1[RB], a2[RB];
#pragma unroll
  for (int r = 0; r < RB; ++r) { a1[r] = 0.f; a2[r] = 0.f; }
#pragma unroll 2
  for (int k = 0; k < DC; ++k) {
    float w1 = W1[(long)k * DC + d];
    float w2 = W2[(long)k * DC + d];
#pragma unroll
    for (int r = 0; r < RB; ++r) {
      a1[r] += xs[r][k] * w1;
      a2[r] += xs[r][k] * w2;
    }
  }
  float bv1 = b1 ? b1[d] : 0.f, bv2 = b2 ? b2[d] : 0.f;
#pragma unroll
  for (int r = 0; r < RB; ++r) {
    int rr = r0 + r;
    float v1 = a1[r] + bv1, v2 = a2[r] + bv2;
    if (!trans) {
      Y1[(long)rr * DC + d] = v1;
      Y2[(long)rr * DC + d] = v2;
    } else {
      int b = rr / rpb, rin = rr - b * rpb;
      Y1[((long)b * DC + d) * rpb + rin] = v1;
      Y2[((long)b * DC + d) * rpb + rin] = v2;
    }
  }
}

// transpose all 6 GRU weight matrices [384][128] -> [128][384] in one go
__global__ void k_tall(const float* __restrict__ IH, const float* __restrict__ HH,
                       float* __restrict__ GIHT, float* __restrict__ GHHT) {
  long idx = (long)blockIdx.x * 256 + threadIdx.x;
  if (idx >= 6L * 49152) return;
  int a = (int)(idx / 49152);
  int rem = (int)(idx % 49152);
  int l = a >> 1, whh = a & 1;
  int c = rem / 384, rr = rem % 384;
  const float* src = (whh ? HH : IH) + (long)l * 49152;
  float* dst = (whh ? GHHT : GIHT) + (long)l * 49152;
  dst[(long)c * 384 + rr] = src[(long)rr * 128 + c];
}

// ---------------------------------------------------------------------------
// Pairwise physics + analytic grad/Hessian partials (unchanged, verified).
// ---------------------------------------------------------------------------
__global__ __launch_bounds__(256) void k_pair(
    const float* __restrict__ UA, const float* __restrict__ VAT,
    const float* __restrict__ UB, const float* __restrict__ VBT,
    const float* __restrict__ AW2, const float* __restrict__ AB2,
    const float* __restrict__ BW2, const float* __restrict__ BB2,
    const float* __restrict__ LP, const float* __restrict__ TP,
    const float* __restrict__ LVDW, const float* __restrict__ TVDW,
    const float* __restrict__ LNM, const float* __restrict__ TNM,
    const float* __restrict__ II, const float* __restrict__ HBC,
    const float* __restrict__ HPC, float* __restrict__ PART) {
  const int D = DC, N1 = N1C, N2 = N2C;
  int i = blockIdx.x, b = blockIdx.y, j = threadIdx.x;
  __shared__ float ua[128], ub[128], wa2[128], wb2[128];
  if (j < 128) {
    long rb = ((long)b * N1 + i) * D + j;
    ua[j] = UA[rb];
    ub[j] = UB[rb];
    wa2[j] = AW2[j];
    wb2[j] = BW2[j];
  }
  __syncthreads();
  const float* vat = VAT + (long)b * D * N2;
  const float* vbt = VBT + (long)b * D * N2;
  float dotA = 0.f, dotB = 0.f;
#pragma unroll 4
  for (int d = 0; d < D; ++d) {
    dotA += fmaxf(ua[d] + vat[(long)d * N2 + j], 0.f) * wa2[d];
    dotB += fmaxf(ub[d] + vbt[(long)d * N2 + j], 0.f) * wb2[d];
  }
  float A_raw = 1.f / (1.f + expf(-(dotA + AB2[0])));
  float A_vdw = A_raw * (0.0356f - 0.0178f) + 0.0178f;
  float B_raw = tanhf(dotB + BB2[0]) * 0.2f;

  float lx = LP[((long)b * N1 + i) * 3 + 0];
  float ly = LP[((long)b * N1 + i) * 3 + 1];
  float lz = LP[((long)b * N1 + i) * 3 + 2];
  float tx = TP[((long)b * N2 + j) * 3 + 0];
  float ty = TP[((long)b * N2 + j) * 3 + 1];
  float tz = TP[((long)b * N2 + j) * 3 + 2];
  float dx = lx - tx, dy = ly - ty, dz = lz - tz;
  float s2 = dx * dx + dy * dy + dz * dz + 1e-10f;
  float draw = sqrtf(s2);
  bool clamped = draw < 0.5f;
  float dmv = clamped ? 1e10f : draw;

  float dm0 = LVDW[b * N1 + i] + TVDW[b * N2 + j] + B_raw;
  float dm0c = (dm0 < 1e-4f) ? 1.f : dm0;
  float valid = LNM[b * N1 + i] * TNM[b * N2 + j];

  float rr = dm0c / dmv;
  float r2 = rr * rr, r6 = r2 * r2 * r2;
  float fv = r6 * r6 - 2.f * r6;
  float evdw = A_vdw * (fminf(fv, 100.f) * valid);

  float dmd = dmv - dm0;
  long ii0 = ((long)b * 3) * N1 * N2 + (long)i * N2 + j;
  float I0 = II[ii0];
  float I1 = II[ii0 + (long)N1 * N2];
  float I2 = II[ii0 + 2L * N1 * N2];
  float hb2 = HBC[0] * HBC[0], hp2 = HPC[0] * HPC[0];
  float u0 = dmd * I0 / (-0.7f);
  float u1 = dmd * I1 / (-0.7f);
  float vv = (1.5f - dmd) * I2;
  float ehb = fminf(fmaxf(u0, 0.f), 1.f) * (-hb2);
  float emt = fminf(fmaxf(u1, 0.f), 1.f) * (-hb2);
  float ehp = fminf(fmaxf(vv, 0.f), 1.f) * (-hp2);

  float gx = 0.f, gy = 0.f, gz = 0.f, d2t = 0.f;
  if (!clamped) {
    float Ep = 0.f, Epp = 0.f;
    if (fv < 100.f) {
      float c = A_vdw * valid;
      Ep += c * (-12.f) * r6 * (r6 - 1.f) / draw;
      Epp += c * r6 * (156.f * r6 - 84.f) / s2;
    }
    if (u0 > 0.f && u0 < 1.f) Ep += hb2 * I0 * (1.f / 0.7f);
    if (u1 > 0.f && u1 < 1.f) Ep += hb2 * I1 * (1.f / 0.7f);
    if (vv > 0.f && vv < 1.f) Ep += hp2 * I2;
    float invd = 1.f / draw;
    gx = Ep * dx * invd;
    gy = Ep * dy * invd;
    gz = Ep * dz * invd;
    float T = dx + dy + dz;
    float tt = T * T / s2;
    d2t = Epp * tt + Ep * (3.f - tt) * invd;
  }

  float o0 = blockSum(evdw);
  float o1 = blockSum(ehb);
  float o2 = blockSum(emt);
  float o3 = blockSum(ehp);
  float o4 = blockSum(gx);
  float o5 = blockSum(gy);
  float o6 = blockSum(gz);
  float o7 = blockSum(d2t);
  if (j == 0) {
    float* p = PART + ((long)b * N1 + i) * 8;
    p[0] = o0; p[1] = o1; p[2] = o2; p[3] = o3;
    p[4] = o4; p[5] = o5; p[6] = o6; p[7] = o7;
  }
}

// final deterministic reduction + output assembly (34 floats)
__global__ void k_final(const float* __restrict__ PART, const float* __restrict__ ROT,
                        const float* __restrict__ RC, float* __restrict__ OUT) {
  const int N1 = N1C;
  __shared__ float s[8][8];
  int t = threadIdx.x;
  if (t < 64) {
    int b = t >> 3, k1 = t & 7;
    float acc = 0.f;
    for (int i = 0; i < N1; ++i) acc += PART[((long)b * N1 + i) * 8 + k1];
    s[b][k1] = acc;
  }
  __syncthreads();
  if (t == 0) {
    float rcc = RC[0] * RC[0];
    float der1 = 0.f, der2 = 0.f;
    for (int b = 0; b < 8; ++b) {
      float w = 1.f / (1.f + rcc * ROT[b]);
      OUT[b * 4 + 0] = s[b][0] * w;
      OUT[b * 4 + 1] = s[b][1] * w;
      OUT[b * 4 + 2] = s[b][2] * w;
      OUT[b * 4 + 3] = s[b][3] * w;
      for (int c = 0; c < 3; ++c) {
        float S = s[b][4 + c] * w;
        der1 += S * S;
      }
      der2 += s[b][7] * w;
    }
    OUT[32] = der1 / 24.f;
    OUT[33] = -der2 / 8.f;
  }
}

// ---------------------------------------------------------------------------
// Host-side orchestration
// ---------------------------------------------------------------------------
extern "C" void kernel_launch(void* const* d_in, const int* in_sizes, int n_in,
                              void* d_out, int out_size, void* d_ws, size_t ws_size,
                              hipStream_t stream) {
  (void)in_sizes; (void)n_in; (void)out_size; (void)ws_size;
  const int D = DC;

  const float* ligand_h   = (const float*)d_in[0];
  const float* ligand_adj = (const float*)d_in[1];
  const float* target_h   = (const float*)d_in[2];
  const float* target_adj = (const float*)d_in[3];
  const float* inter_ind  = (const float*)d_in[4];
  const float* ligand_pos = (const float*)d_in[5];
  const float* target_pos = (const float*)d_in[6];
  const float* rotor      = (const float*)d_in[7];
  const float* lvdw       = (const float*)d_in[8];
  const float* tvdw       = (const float*)d_in[9];
  const float* lnm        = (const float*)d_in[12];
  const float* tnm        = (const float*)d_in[13];
  const float* emb_w      = (const float*)d_in[14];
  const float* gat_w      = (const float*)d_in[15];
  const float* gat_b      = (const float*)d_in[16];
  const float* gat_att    = (const float*)d_in[17];
  const float* gat_gate_w = (const float*)d_in[18];
  const float* gat_gate_b = (const float*)d_in[19];
  const float* int_wt_w   = (const float*)d_in[20];
  const float* int_wt_b   = (const float*)d_in[21];
  const float* int_mt_w   = (const float*)d_in[22];
  const float* int_mt_b   = (const float*)d_in[23];
  const float* gru_w_ih   = (const float*)d_in[24];
  const float* gru_w_hh   = (const float*)d_in[25];
  const float* gru_b_ih   = (const float*)d_in[26];
  const float* gru_b_hh   = (const float*)d_in[27];
  const float* A_w1       = (const float*)d_in[28];
  const float* A_b1       = (const float*)d_in[29];
  const float* A_w2       = (const float*)d_in[30];
  const float* A_b2       = (const float*)d_in[31];
  const float* B_w1       = (const float*)d_in[32];
  const float* B_b1       = (const float*)d_in[33];
  const float* B_w2       = (const float*)d_in[34];
  const float* B_b2       = (const float*)d_in[35];
  const float* hb_c       = (const float*)d_in[36];
  const float* hp_c       = (const float*)d_in[37];
  const float* rc_c       = (const float*)d_in[38];

  // workspace carve (floats)
  float* w = (float*)d_ws;
  auto take = [&](size_t n) { float* p = w; w += n; return p; };
  float* H0    = take((size_t)ROWS_ALL * DC);  // 393216
  float* H1    = take((size_t)ROWS_ALL * DC);
  float* NT    = take((size_t)ROWS_ALL * DC);
  float* E1    = take((size_t)ROWS_ALL * DC);
  float* OUTB  = take((size_t)ROWS_ALL * DC);
  float* ADJ12 = take((size_t)BB * N1C * N2C);  // 262144
  float* GIHT  = take((size_t)3 * DC * 384);    // 147456
  float* GHHT  = take((size_t)3 * DC * 384);
  float* PART  = take((size_t)BB * N1C * 8);
  // phase-disjoint aliases
  float* T1  = NT;
  float* M2  = E1;
  float* MSG = OUTB;
  float* UA  = NT;             // 131072
  float* UB  = NT + 131072;    // within NT's 393216
  float* VAT = E1;             // 262144
  float* VBT = OUTB;           // 262144

  // geometry adjacency
  k_adj12<<<(BB * N1C * N2C + 255) / 256, 256, 0, stream>>>(ligand_pos,
                                                            target_pos, ADJ12);
  // embedding (both graphs, packed)
  k_emb<<<ROWS_ALL / 8, 128, 0, stream>>>(ligand_h, target_h, emb_w, H0);

  float *cur = H0, *alt = H1;

  // GAT stack (3 layers, both graphs per dispatch)
  for (int l = 0; l < 3; ++l) {
    k_nte1<<<ROWS_ALL / 8, 128, 0, stream>>>(cur, gat_w + (size_t)l * D * D,
                                             gat_b + l * D,
                                             gat_att + (size_t)l * D * D, NT, E1);
    k_attn<N1C><<<dim3(N1C / 16, BB), 256, 0, stream>>>(NT, E1, ligand_adj,
                                                        OUTB, 0);
    k_attn<N2C><<<dim3(N2C / 16, BB), 256, 0, stream>>>(NT, E1, target_adj,
                                                        OUTB, ROWS_L);
    k_gate<<<ROWS_ALL, 128, 0, stream>>>(cur, OUTB, gat_gate_w + l * 2 * D,
                                         gat_gate_b + l, alt);
    float* t = cur; cur = alt; alt = t;
  }

  // GRU weight transposes (single dispatch)
  k_tall<<<(6 * 49152 + 255) / 256, 256, 0, stream>>>(gru_w_ih, gru_w_hh, GIHT,
                                                      GHHT);

  // interaction layers (both directions per dispatch; both use OLD h)
  for (int l = 0; l < 3; ++l) {
    k_feat2<8><<<ROWS_ALL / 8, 128, 0, stream>>>(
        cur, int_wt_w + (size_t)l * D * D, int_wt_b + l * D,
        int_mt_w + (size_t)l * D * D, int_mt_b + l * D, T1, M2, 1, 0);
    k_msg2z<<<dim3(N2C / 8, BB, 2), 256, 0, stream>>>(T1, M2, ADJ12, MSG);
    k_gruf<<<ROWS_ALL / 8, 384, 0, stream>>>(MSG, cur, GIHT + (size_t)l * D * 384,
                                             GHHT + (size_t)l * D * 384,
                                             gru_b_ih + l * 384,
                                             gru_b_hh + l * 384, alt);
    float* t = cur; cur = alt; alt = t;
  }

  // pairwise feature precompute (U normal layout, V transposed [b][d][j])
  k_feat2<8><<<ROWS_L / 8, 128, 0, stream>>>(cur, A_w1, A_b1, B_w1, B_b1, UA, UB,
                                             1, 0);
  k_feat2<8><<<ROWS_T / 8, 128, 0, stream>>>(cur + (size_t)ROWS_L * DC,
                                             A_w1 + D * D, nullptr, B_w1 + D * D,
                                             nullptr, VAT, VBT, N2C, 1);

  // pairwise physics + analytic derivatives
  k_pair<<<dim3(N1C, BB), 256, 0, stream>>>(UA, VAT, UB, VBT, A_w2, A_b2, B_w2,
                                            B_b2, ligand_pos, target_pos, lvdw,
                                            tvdw, lnm, tnm, inter_ind, hb_c,
                                            hp_c, PART);

  // final reduction -> 34 outputs
  k_final<<<1, 256, 0, stream>>>(PART, rotor, rc_c, (float*)d_out);
}

// Round 4
// 616.318 us; speedup vs baseline: 1.6532x; 1.6532x over previous
//
#include <hip/hip_runtime.h>
#include <math.h>

// ---------------------------------------------------------------------------
// Problem constants (B=8, N1=128, N2=256, D=128, L=3, NH=54)
// Packed row space: rows 0..1023 = ligand (b*128+i), rows 1024..3071 = target
// (1024 + b*256 + j).  All per-row linears run once over 3072 rows.
// ---------------------------------------------------------------------------
#define BB 8
#define N1C 128
#define N2C 256
#define DC 128
#define NHC 54
#define ROWS_L 1024
#define ROWS_T 2048
#define ROWS_ALL 3072

// ---------------------------------------------------------------------------
// Reductions (wave64)
// ---------------------------------------------------------------------------
__device__ __forceinline__ float wredSum(float v) {
#pragma unroll
  for (int o = 32; o > 0; o >>= 1) v += __shfl_down(v, o);
  return v;
}
__device__ float blockSum(float v) {
  __shared__ float red[9];
  v = wredSum(v);
  int lane = threadIdx.x & 63, wid = threadIdx.x >> 6;
  __syncthreads();
  if (lane == 0) red[wid] = v;
  __syncthreads();
  if (threadIdx.x == 0) {
    float s = 0.f;
    int nw = (blockDim.x + 63) >> 6;
    for (int i = 0; i < nw; ++i) s += red[i];
    red[8] = s;
  }
  __syncthreads();
  return red[8];
}

// ---------------------------------------------------------------------------
// Embedding: H0[r][d] = (r<1024 ? ligand_h[r] : target_h[r-1024]) @ emb_w
// ---------------------------------------------------------------------------
__global__ __launch_bounds__(128) void k_emb(const float* __restrict__ LH,
                                             const float* __restrict__ TH,
                                             const float* __restrict__ W,
                                             float* __restrict__ H0) {
  int r0 = blockIdx.x * 8;
  __shared__ float xs[8][NHC];
  for (int t = threadIdx.x; t < 8 * NHC; t += 128) {
    int rr = r0 + t / NHC, c = t % NHC;
    xs[t / NHC][c] = (rr < ROWS_L) ? LH[(long)rr * NHC + c]
                                   : TH[(long)(rr - ROWS_L) * NHC + c];
  }
  __syncthreads();
  int d = threadIdx.x;
  float acc[8];
#pragma unroll
  for (int r = 0; r < 8; ++r) acc[r] = 0.f;
  for (int k = 0; k < NHC; ++k) {
    float wv = W[(long)k * DC + d];
#pragma unroll
    for (int r = 0; r < 8; ++r) acc[r] += xs[r][k] * wv;
  }
#pragma unroll
  for (int r = 0; r < 8; ++r) H0[(long)(r0 + r) * DC + d] = acc[r];
}

// ---------------------------------------------------------------------------
// Fused GAT linears: NT = X@W + b ; E1 = NT@ATT.  8 rows/block.
// ---------------------------------------------------------------------------
__global__ __launch_bounds__(128) void k_nte1(const float* __restrict__ X,
                                              const float* __restrict__ W,
                                              const float* __restrict__ bias,
                                              const float* __restrict__ ATT,
                                              float* __restrict__ NT,
                                              float* __restrict__ E1) {
  int r0 = blockIdx.x * 8;
  __shared__ float xs[8][DC], nts[8][DC];
  for (int t = threadIdx.x; t < 8 * DC; t += 128)
    xs[t >> 7][t & 127] = X[(long)r0 * DC + t];
  __syncthreads();
  int d = threadIdx.x;
  float acc[8];
#pragma unroll
  for (int r = 0; r < 8; ++r) acc[r] = 0.f;
#pragma unroll 2
  for (int k = 0; k < DC; ++k) {
    float wv = W[(long)k * DC + d];
#pragma unroll
    for (int r = 0; r < 8; ++r) acc[r] += xs[r][k] * wv;
  }
  float bv = bias[d];
#pragma unroll
  for (int r = 0; r < 8; ++r) {
    float v = acc[r] + bv;
    nts[r][d] = v;
    NT[(long)(r0 + r) * DC + d] = v;
  }
  __syncthreads();
#pragma unroll
  for (int r = 0; r < 8; ++r) acc[r] = 0.f;
#pragma unroll 2
  for (int k = 0; k < DC; ++k) {
    float av = ATT[(long)k * DC + d];
#pragma unroll
    for (int r = 0; r < 8; ++r) acc[r] += nts[r][k] * av;
  }
#pragma unroll
  for (int r = 0; r < 8; ++r) E1[(long)(r0 + r) * DC + d] = acc[r];
}

// ---------------------------------------------------------------------------
// ea[b,j,k] = e1_j.nt_k + nt_j.e1_k, masked by adjacency at write time.
// 16x16 tile per block.  grid (N/16, N/16, B), block (16,16).
// ---------------------------------------------------------------------------
template <int N>
__global__ __launch_bounds__(256) void k_ea(const float* __restrict__ NTp,
                                            const float* __restrict__ E1p,
                                            const float* __restrict__ ADJ,
                                            float* __restrict__ EAp,
                                            int baseRow) {
  const int D = DC;
  int b = blockIdx.z;
  int j0 = blockIdx.y * 16, k0 = blockIdx.x * 16;
  int tj = threadIdx.y, tk = threadIdx.x;
  __shared__ float e1j[16][17], ntj[16][17], e1k[16][17], ntk[16][17];
  const float* E1b = E1p + (long)(baseRow + b * N) * D;
  const float* NTb = NTp + (long)(baseRow + b * N) * D;
  float acc = 0.f;
  for (int kk = 0; kk < D; kk += 16) {
    e1j[tj][tk] = E1b[(long)(j0 + tj) * D + kk + tk];
    ntj[tj][tk] = NTb[(long)(j0 + tj) * D + kk + tk];
    e1k[tj][tk] = E1b[(long)(k0 + tj) * D + kk + tk];
    ntk[tj][tk] = NTb[(long)(k0 + tj) * D + kk + tk];
    __syncthreads();
#pragma unroll
    for (int t = 0; t < 16; ++t)
      acc += e1j[tj][t] * ntk[tk][t] + ntj[tj][t] * e1k[tk][t];
    __syncthreads();
  }
  long idx = (long)b * N * N + (long)(j0 + tj) * N + k0 + tk;
  float ad = ADJ[idx];
  EAp[idx] = (ad > 1e-6f) ? acc : -9e15f;
}

// ---------------------------------------------------------------------------
// Fused row-softmax + aggregate + gated residual.
//   P = softmax(EA row); out = relu(P @ NT); g = sigmoid([x,out].gw+gb);
//   Y = g*x + (1-g)*out.   8 rows per block, 256 threads, grid (N/8, B).
// ---------------------------------------------------------------------------
template <int N>
__global__ __launch_bounds__(256) void k_smagg(
    const float* __restrict__ EAp, const float* __restrict__ NTp,
    const float* __restrict__ Xp, const float* __restrict__ GW,
    const float* __restrict__ GB, float* __restrict__ Y, int baseRow) {
  __shared__ float ps[8][N + 4];
  __shared__ float col[32][DC + 4];
  __shared__ float red[4][4];
  int b = blockIdx.y, i0 = blockIdx.x * 8;
  int tid = threadIdx.x;
  const float* EAb = EAp + (long)b * N * N + (long)i0 * N;
  for (int t = tid; t < 8 * N; t += 256) ps[t / N][t % N] = EAb[(long)(t / N) * N + (t % N)];
  __syncthreads();
  {  // softmax: 32 lanes per row
    int r = tid >> 5, l = tid & 31;
    float m = -INFINITY;
    for (int k = l; k < N; k += 32) m = fmaxf(m, ps[r][k]);
#pragma unroll
    for (int o = 16; o > 0; o >>= 1) m = fmaxf(m, __shfl_xor(m, o));
    float s = 0.f;
    for (int k = l; k < N; k += 32) {
      float p = expf(ps[r][k] - m);
      ps[r][k] = p;
      s += p;
    }
#pragma unroll
    for (int o = 16; o > 0; o >>= 1) s += __shfl_xor(s, o);
    float inv = 1.f / s;
    for (int k = l; k < N; k += 32) ps[r][k] *= inv;
  }
  // aggregate: thread owns (d = tid&127) for rows ro, ro+2, ro+4, ro+6
  int d = tid & 127, ro = tid >> 7;
  float acc[4] = {0.f, 0.f, 0.f, 0.f};
  const float* NTb = NTp + (long)(baseRow + b * N) * DC;
  for (int k0 = 0; k0 < N; k0 += 32) {
    __syncthreads();
    for (int t = tid; t < 32 * DC; t += 256)
      col[t >> 7][t & 127] = NTb[(long)(k0 + (t >> 7)) * DC + (t & 127)];
    __syncthreads();
#pragma unroll 8
    for (int kk = 0; kk < 32; ++kk) {
      float cv = col[kk][d];
#pragma unroll
      for (int q = 0; q < 4; ++q) acc[q] = fmaf(ps[ro + 2 * q][k0 + kk], cv, acc[q]);
    }
  }
  // fused gate
  float gwd = GW[d], gwo = GW[DC + d];
  float xv[4], part[4];
#pragma unroll
  for (int q = 0; q < 4; ++q) {
    int r = ro + 2 * q;
    float o = fmaxf(acc[q], 0.f);
    acc[q] = o;
    float x = Xp[(long)(baseRow + b * N + i0 + r) * DC + d];
    xv[q] = x;
    part[q] = x * gwd + o * gwo;
  }
  int wid = tid >> 6;
#pragma unroll
  for (int q = 0; q < 4; ++q) {
    float v = wredSum(part[q]);
    if ((tid & 63) == 0) red[wid][q] = v;
  }
  __syncthreads();
  float gb = GB[0];
#pragma unroll
  for (int q = 0; q < 4; ++q) {
    int r = ro + 2 * q;
    float s = red[ro * 2][q] + red[ro * 2 + 1][q];
    float g = 1.f / (1.f + expf(-(s + gb)));
    Y[(long)(baseRow + b * N + i0 + r) * DC + d] = g * xv[q] + (1.f - g) * acc[q];
  }
}

// adj12 from positions
__global__ void k_adj12(const float* __restrict__ LP, const float* __restrict__ TP,
                        float* __restrict__ AD) {
  long idx = (long)blockIdx.x * blockDim.x + threadIdx.x;
  if (idx >= (long)BB * N1C * N2C) return;
  int j = idx & (N2C - 1);
  long t = idx >> 8;
  int i = (int)(t & (N1C - 1));
  int b = (int)(t >> 7);
  float dx = LP[((long)b * N1C + i) * 3 + 0] - TP[((long)b * N2C + j) * 3 + 0];
  float dy = LP[((long)b * N1C + i) * 3 + 1] - TP[((long)b * N2C + j) * 3 + 1];
  float dz = LP[((long)b * N1C + i) * 3 + 2] - TP[((long)b * N2C + j) * 3 + 2];
  float d = sqrtf(dx * dx + dy * dy + dz * dz + 1e-10f);
  if (d < 0.5f) d = 1e10f;
  AD[idx] = (d <= 5.0f && d > 1e-3f) ? 1.f : 0.f;
}

// ---------------------------------------------------------------------------
// Merged msg kernel: z=0 ligand update (Ni=128,Nj=256), z=1 target update
// (Ni=256,Nj=128, transposed EV access).  msg = relu(t1 + max_j m2_j*ev_ij).
// ---------------------------------------------------------------------------
__global__ __launch_bounds__(256) void k_msg2z(const float* __restrict__ T1,
                                               const float* __restrict__ M2,
                                               const float* __restrict__ EV,
                                               float* __restrict__ MSG) {
  int z = blockIdx.z, b = blockIdx.y;
  int Ni = z ? N2C : N1C, Nj = z ? N1C : N2C;
  int t1off = z ? ROWS_L : 0, m2off = z ? 0 : ROWS_L;
  long ev_is = z ? 1L : (long)N2C, ev_js = z ? (long)N2C : 1L;
  int i0 = blockIdx.x * 8;
  if (i0 >= Ni) return;
  __shared__ float m2s[32][DC];
  __shared__ float evs[8][32];
  int d = threadIdx.x & 127, io = threadIdx.x >> 7;
  float acc[4];
#pragma unroll
  for (int q = 0; q < 4; ++q) acc[q] = -INFINITY;
  const float* M2b = M2 + (long)(m2off + b * Nj) * DC;
  const float* EVb = EV + (long)b * (N1C * N2C);
  for (int j0 = 0; j0 < Nj; j0 += 32) {
    __syncthreads();
    for (int t = threadIdx.x; t < 32 * DC; t += 256)
      m2s[t >> 7][t & 127] = M2b[(long)(j0 + (t >> 7)) * DC + (t & 127)];
    for (int t = threadIdx.x; t < 8 * 32; t += 256)
      evs[t >> 5][t & 31] =
          EVb[(long)(i0 + (t >> 5)) * ev_is + (long)(j0 + (t & 31)) * ev_js];
    __syncthreads();
#pragma unroll 8
    for (int jj = 0; jj < 32; ++jj) {
      float m2v = m2s[jj][d];
#pragma unroll
      for (int q = 0; q < 4; ++q)
        acc[q] = fmaxf(acc[q], m2v * evs[io + 2 * q][jj]);
    }
  }
#pragma unroll
  for (int q = 0; q < 4; ++q) {
    int i = i0 + io + 2 * q;
    long row = t1off + (long)b * Ni + i;
    MSG[row * DC + d] = fmaxf(T1[row * DC + d] + acc[q], 0.f);
  }
}

// ---------------------------------------------------------------------------
// Fused GRU over all 3072 rows: gi = msg@WihT+bih, gh = h@WhhT+bhh, combine.
// ---------------------------------------------------------------------------
__global__ __launch_bounds__(384) void k_gruf(
    const float* __restrict__ MSGp, const float* __restrict__ Hp,
    const float* __restrict__ WihT, const float* __restrict__ WhhT,
    const float* __restrict__ bih, const float* __restrict__ bhh,
    float* __restrict__ Y) {
  const int D = DC;
  int r0 = blockIdx.x * 8;
  __shared__ float xs[8][DC], hs[8][DC];
  __shared__ float gis[8][384], ghs[8][384];
  for (int t = threadIdx.x; t < 8 * DC; t += 384) {
    int r = t >> 7, c = t & 127;
    xs[r][c] = MSGp[(long)(r0 + r) * D + c];
    hs[r][c] = Hp[(long)(r0 + r) * D + c];
  }
  __syncthreads();
  int dd = threadIdx.x;
  float ai[8], ah[8];
#pragma unroll
  for (int r = 0; r < 8; ++r) { ai[r] = 0.f; ah[r] = 0.f; }
#pragma unroll 2
  for (int k = 0; k < DC; ++k) {
    float wi = WihT[(long)k * 384 + dd];
    float wh = WhhT[(long)k * 384 + dd];
#pragma unroll
    for (int r = 0; r < 8; ++r) {
      ai[r] += xs[r][k] * wi;
      ah[r] += hs[r][k] * wh;
    }
  }
  float bi = bih[dd], bh = bhh[dd];
#pragma unroll
  for (int r = 0; r < 8; ++r) {
    gis[r][dd] = ai[r] + bi;
    ghs[r][dd] = ah[r] + bh;
  }
  __syncthreads();
  for (int t = threadIdx.x; t < 8 * DC; t += 384) {
    int r = t >> 7, d = t & 127;
    float ir = gis[r][d], iz = gis[r][d + 128], inn = gis[r][d + 256];
    float hr = ghs[r][d], hz = ghs[r][d + 128], hn = ghs[r][d + 256];
    float rg = 1.f / (1.f + expf(-(ir + hr)));
    float zg = 1.f / (1.f + expf(-(iz + hz)));
    float ng = tanhf(inn + rg * hn);
    Y[(long)(r0 + r) * D + d] = (1.f - zg) * ng + zg * hs[r][d];
  }
}

// ---------------------------------------------------------------------------
// Dual-head linear: Y1 = X@W1(+b1), Y2 = X@W2(+b2).  K=Dout=128.
// trans=1 stores transposed per batch: Y[b][d][row_in_batch].
// ---------------------------------------------------------------------------
template <int RB>
__global__ __launch_bounds__(128) void k_feat2(
    const float* __restrict__ X, const float* __restrict__ W1,
    const float* __restrict__ b1, const float* __restrict__ W2,
    const float* __restrict__ b2, float* __restrict__ Y1, float* __restrict__ Y2,
    int rpb, int trans) {
  int r0 = blockIdx.x * RB;
  __shared__ float xs[RB][DC];
  for (int t = threadIdx.x; t < RB * DC; t += 128)
    xs[t >> 7][t & 127] = X[(long)(r0 + (t >> 7)) * DC + (t & 127)];
  __syncthreads();
  int d = threadIdx.x;
  float a1[RB], a2[RB];
#pragma unroll
  for (int r = 0; r < RB; ++r) { a1[r] = 0.f; a2[r] = 0.f; }
#pragma unroll 2
  for (int k = 0; k < DC; ++k) {
    float w1 = W1[(long)k * DC + d];
    float w2 = W2[(long)k * DC + d];
#pragma unroll
    for (int r = 0; r < RB; ++r) {
      a1[r] += xs[r][k] * w1;
      a2[r] += xs[r][k] * w2;
    }
  }
  float bv1 = b1 ? b1[d] : 0.f, bv2 = b2 ? b2[d] : 0.f;
#pragma unroll
  for (int r = 0; r < RB; ++r) {
    int rr = r0 + r;
    float v1 = a1[r] + bv1, v2 = a2[r] + bv2;
    if (!trans) {
      Y1[(long)rr * DC + d] = v1;
      Y2[(long)rr * DC + d] = v2;
    } else {
      int b = rr / rpb, rin = rr - b * rpb;
      Y1[((long)b * DC + d) * rpb + rin] = v1;
      Y2[((long)b * DC + d) * rpb + rin] = v2;
    }
  }
}

// transpose all 6 GRU weight matrices [384][128] -> [128][384] in one go
__global__ void k_tall(const float* __restrict__ IH, const float* __restrict__ HH,
                       float* __restrict__ GIHT, float* __restrict__ GHHT) {
  long idx = (long)blockIdx.x * 256 + threadIdx.x;
  if (idx >= 6L * 49152) return;
  int a = (int)(idx / 49152);
  int rem = (int)(idx % 49152);
  int l = a >> 1, whh = a & 1;
  int c = rem / 384, rr = rem % 384;
  const float* src = (whh ? HH : IH) + (long)l * 49152;
  float* dst = (whh ? GHHT : GIHT) + (long)l * 49152;
  dst[(long)c * 384 + rr] = src[(long)rr * 128 + c];
}

// ---------------------------------------------------------------------------
// Pairwise physics + analytic grad/Hessian partials (verified).
// ---------------------------------------------------------------------------
__global__ __launch_bounds__(256) void k_pair(
    const float* __restrict__ UA, const float* __restrict__ VAT,
    const float* __restrict__ UB, const float* __restrict__ VBT,
    const float* __restrict__ AW2, const float* __restrict__ AB2,
    const float* __restrict__ BW2, const float* __restrict__ BB2,
    const float* __restrict__ LP, const float* __restrict__ TP,
    const float* __restrict__ LVDW, const float* __restrict__ TVDW,
    const float* __restrict__ LNM, const float* __restrict__ TNM,
    const float* __restrict__ II, const float* __restrict__ HBC,
    const float* __restrict__ HPC, float* __restrict__ PART) {
  const int D = DC, N1 = N1C, N2 = N2C;
  int i = blockIdx.x, b = blockIdx.y, j = threadIdx.x;
  __shared__ float ua[128], ub[128], wa2[128], wb2[128];
  if (j < 128) {
    long rb = ((long)b * N1 + i) * D + j;
    ua[j] = UA[rb];
    ub[j] = UB[rb];
    wa2[j] = AW2[j];
    wb2[j] = BW2[j];
  }
  __syncthreads();
  const float* vat = VAT + (long)b * D * N2;
  const float* vbt = VBT + (long)b * D * N2;
  float dotA = 0.f, dotB = 0.f;
#pragma unroll 4
  for (int d = 0; d < D; ++d) {
    dotA += fmaxf(ua[d] + vat[(long)d * N2 + j], 0.f) * wa2[d];
    dotB += fmaxf(ub[d] + vbt[(long)d * N2 + j], 0.f) * wb2[d];
  }
  float A_raw = 1.f / (1.f + expf(-(dotA + AB2[0])));
  float A_vdw = A_raw * (0.0356f - 0.0178f) + 0.0178f;
  float B_raw = tanhf(dotB + BB2[0]) * 0.2f;

  float lx = LP[((long)b * N1 + i) * 3 + 0];
  float ly = LP[((long)b * N1 + i) * 3 + 1];
  float lz = LP[((long)b * N1 + i) * 3 + 2];
  float tx = TP[((long)b * N2 + j) * 3 + 0];
  float ty = TP[((long)b * N2 + j) * 3 + 1];
  float tz = TP[((long)b * N2 + j) * 3 + 2];
  float dx = lx - tx, dy = ly - ty, dz = lz - tz;
  float s2 = dx * dx + dy * dy + dz * dz + 1e-10f;
  float draw = sqrtf(s2);
  bool clamped = draw < 0.5f;
  float dmv = clamped ? 1e10f : draw;

  float dm0 = LVDW[b * N1 + i] + TVDW[b * N2 + j] + B_raw;
  float dm0c = (dm0 < 1e-4f) ? 1.f : dm0;
  float valid = LNM[b * N1 + i] * TNM[b * N2 + j];

  float rr = dm0c / dmv;
  float r2 = rr * rr, r6 = r2 * r2 * r2;
  float fv = r6 * r6 - 2.f * r6;
  float evdw = A_vdw * (fminf(fv, 100.f) * valid);

  float dmd = dmv - dm0;
  long ii0 = ((long)b * 3) * N1 * N2 + (long)i * N2 + j;
  float I0 = II[ii0];
  float I1 = II[ii0 + (long)N1 * N2];
  float I2 = II[ii0 + 2L * N1 * N2];
  float hb2 = HBC[0] * HBC[0], hp2 = HPC[0] * HPC[0];
  float u0 = dmd * I0 / (-0.7f);
  float u1 = dmd * I1 / (-0.7f);
  float vv = (1.5f - dmd) * I2;
  float ehb = fminf(fmaxf(u0, 0.f), 1.f) * (-hb2);
  float emt = fminf(fmaxf(u1, 0.f), 1.f) * (-hb2);
  float ehp = fminf(fmaxf(vv, 0.f), 1.f) * (-hp2);

  float gx = 0.f, gy = 0.f, gz = 0.f, d2t = 0.f;
  if (!clamped) {
    float Ep = 0.f, Epp = 0.f;
    if (fv < 100.f) {
      float c = A_vdw * valid;
      Ep += c * (-12.f) * r6 * (r6 - 1.f) / draw;
      Epp += c * r6 * (156.f * r6 - 84.f) / s2;
    }
    if (u0 > 0.f && u0 < 1.f) Ep += hb2 * I0 * (1.f / 0.7f);
    if (u1 > 0.f && u1 < 1.f) Ep += hb2 * I1 * (1.f / 0.7f);
    if (vv > 0.f && vv < 1.f) Ep += hp2 * I2;
    float invd = 1.f / draw;
    gx = Ep * dx * invd;
    gy = Ep * dy * invd;
    gz = Ep * dz * invd;
    float T = dx + dy + dz;
    float tt = T * T / s2;
    d2t = Epp * tt + Ep * (3.f - tt) * invd;
  }

  float o0 = blockSum(evdw);
  float o1 = blockSum(ehb);
  float o2 = blockSum(emt);
  float o3 = blockSum(ehp);
  float o4 = blockSum(gx);
  float o5 = blockSum(gy);
  float o6 = blockSum(gz);
  float o7 = blockSum(d2t);
  if (j == 0) {
    float* p = PART + ((long)b * N1 + i) * 8;
    p[0] = o0; p[1] = o1; p[2] = o2; p[3] = o3;
    p[4] = o4; p[5] = o5; p[6] = o6; p[7] = o7;
  }
}

// final deterministic reduction + output assembly (34 floats)
__global__ void k_final(const float* __restrict__ PART, const float* __restrict__ ROT,
                        const float* __restrict__ RC, float* __restrict__ OUT) {
  const int N1 = N1C;
  __shared__ float s[8][8];
  int t = threadIdx.x;
  if (t < 64) {
    int b = t >> 3, k1 = t & 7;
    float acc = 0.f;
    for (int i = 0; i < N1; ++i) acc += PART[((long)b * N1 + i) * 8 + k1];
    s[b][k1] = acc;
  }
  __syncthreads();
  if (t == 0) {
    float rcc = RC[0] * RC[0];
    float der1 = 0.f, der2 = 0.f;
    for (int b = 0; b < 8; ++b) {
      float w = 1.f / (1.f + rcc * ROT[b]);
      OUT[b * 4 + 0] = s[b][0] * w;
      OUT[b * 4 + 1] = s[b][1] * w;
      OUT[b * 4 + 2] = s[b][2] * w;
      OUT[b * 4 + 3] = s[b][3] * w;
      for (int c = 0; c < 3; ++c) {
        float S = s[b][4 + c] * w;
        der1 += S * S;
      }
      der2 += s[b][7] * w;
    }
    OUT[32] = der1 / 24.f;
    OUT[33] = -der2 / 8.f;
  }
}

// ---------------------------------------------------------------------------
// Host-side orchestration
// ---------------------------------------------------------------------------
extern "C" void kernel_launch(void* const* d_in, const int* in_sizes, int n_in,
                              void* d_out, int out_size, void* d_ws, size_t ws_size,
                              hipStream_t stream) {
  (void)in_sizes; (void)n_in; (void)out_size; (void)ws_size;
  const int D = DC;

  const float* ligand_h   = (const float*)d_in[0];
  const float* ligand_adj = (const float*)d_in[1];
  const float* target_h   = (const float*)d_in[2];
  const float* target_adj = (const float*)d_in[3];
  const float* inter_ind  = (const float*)d_in[4];
  const float* ligand_pos = (const float*)d_in[5];
  const float* target_pos = (const float*)d_in[6];
  const float* rotor      = (const float*)d_in[7];
  const float* lvdw       = (const float*)d_in[8];
  const float* tvdw       = (const float*)d_in[9];
  const float* lnm        = (const float*)d_in[12];
  const float* tnm        = (const float*)d_in[13];
  const float* emb_w      = (const float*)d_in[14];
  const float* gat_w      = (const float*)d_in[15];
  const float* gat_b      = (const float*)d_in[16];
  const float* gat_att    = (const float*)d_in[17];
  const float* gat_gate_w = (const float*)d_in[18];
  const float* gat_gate_b = (const float*)d_in[19];
  const float* int_wt_w   = (const float*)d_in[20];
  const float* int_wt_b   = (const float*)d_in[21];
  const float* int_mt_w   = (const float*)d_in[22];
  const float* int_mt_b   = (const float*)d_in[23];
  const float* gru_w_ih   = (const float*)d_in[24];
  const float* gru_w_hh   = (const float*)d_in[25];
  const float* gru_b_ih   = (const float*)d_in[26];
  const float* gru_b_hh   = (const float*)d_in[27];
  const float* A_w1       = (const float*)d_in[28];
  const float* A_b1       = (const float*)d_in[29];
  const float* A_w2       = (const float*)d_in[30];
  const float* A_b2       = (const float*)d_in[31];
  const float* B_w1       = (const float*)d_in[32];
  const float* B_b1       = (const float*)d_in[33];
  const float* B_w2       = (const float*)d_in[34];
  const float* B_b2       = (const float*)d_in[35];
  const float* hb_c       = (const float*)d_in[36];
  const float* hp_c       = (const float*)d_in[37];
  const float* rc_c       = (const float*)d_in[38];

  // workspace carve (floats)
  float* w = (float*)d_ws;
  auto take = [&](size_t n) { float* p = w; w += n; return p; };
  float* H0    = take((size_t)ROWS_ALL * DC);  // 393216
  float* H1    = take((size_t)ROWS_ALL * DC);
  float* NT    = take((size_t)ROWS_ALL * DC);
  float* E1    = take((size_t)ROWS_ALL * DC);
  float* OUTB  = take((size_t)ROWS_ALL * DC);
  float* ADJ12 = take((size_t)BB * N1C * N2C);  // 262144
  float* EA    = take((size_t)BB * N2C * N2C);  // 524288
  float* GIHT  = take((size_t)3 * DC * 384);    // 147456
  float* GHHT  = take((size_t)3 * DC * 384);
  float* PART  = take((size_t)BB * N1C * 8);
  // phase-disjoint aliases
  float* T1  = NT;
  float* M2  = E1;
  float* MSG = OUTB;
  float* UA  = NT;             // 131072
  float* UB  = NT + 131072;    // within NT's 393216
  float* VAT = E1;             // 262144
  float* VBT = OUTB;           // 262144

  // geometry adjacency
  k_adj12<<<(BB * N1C * N2C + 255) / 256, 256, 0, stream>>>(ligand_pos,
                                                            target_pos, ADJ12);
  // embedding (both graphs, packed)
  k_emb<<<ROWS_ALL / 8, 128, 0, stream>>>(ligand_h, target_h, emb_w, H0);

  float *cur = H0, *alt = H1;

  // GAT stack (3 layers)
  for (int l = 0; l < 3; ++l) {
    k_nte1<<<ROWS_ALL / 8, 128, 0, stream>>>(cur, gat_w + (size_t)l * D * D,
                                             gat_b + l * D,
                                             gat_att + (size_t)l * D * D, NT, E1);
    k_ea<N1C><<<dim3(N1C / 16, N1C / 16, BB), dim3(16, 16), 0, stream>>>(
        NT, E1, ligand_adj, EA, 0);
    k_smagg<N1C><<<dim3(N1C / 8, BB), 256, 0, stream>>>(
        EA, NT, cur, gat_gate_w + l * 2 * D, gat_gate_b + l, alt, 0);
    k_ea<N2C><<<dim3(N2C / 16, N2C / 16, BB), dim3(16, 16), 0, stream>>>(
        NT, E1, target_adj, EA, ROWS_L);
    k_smagg<N2C><<<dim3(N2C / 8, BB), 256, 0, stream>>>(
        EA, NT, cur, gat_gate_w + l * 2 * D, gat_gate_b + l, alt, ROWS_L);
    float* t = cur; cur = alt; alt = t;
  }

  // GRU weight transposes (single dispatch)
  k_tall<<<(6 * 49152 + 255) / 256, 256, 0, stream>>>(gru_w_ih, gru_w_hh, GIHT,
                                                      GHHT);

  // interaction layers (both directions per dispatch; both use OLD h)
  for (int l = 0; l < 3; ++l) {
    k_feat2<8><<<ROWS_ALL / 8, 128, 0, stream>>>(
        cur, int_wt_w + (size_t)l * D * D, int_wt_b + l * D,
        int_mt_w + (size_t)l * D * D, int_mt_b + l * D, T1, M2, 1, 0);
    k_msg2z<<<dim3(N2C / 8, BB, 2), 256, 0, stream>>>(T1, M2, ADJ12, MSG);
    k_gruf<<<ROWS_ALL / 8, 384, 0, stream>>>(MSG, cur, GIHT + (size_t)l * D * 384,
                                             GHHT + (size_t)l * D * 384,
                                             gru_b_ih + l * 384,
                                             gru_b_hh + l * 384, alt);
    float* t = cur; cur = alt; alt = t;
  }

  // pairwise feature precompute (U normal layout, V transposed [b][d][j])
  k_feat2<8><<<ROWS_L / 8, 128, 0, stream>>>(cur, A_w1, A_b1, B_w1, B_b1, UA, UB,
                                             1, 0);
  k_feat2<8><<<ROWS_T / 8, 128, 0, stream>>>(cur + (size_t)ROWS_L * DC,
                                             A_w1 + D * D, nullptr, B_w1 + D * D,
                                             nullptr, VAT, VBT, N2C, 1);

  // pairwise physics + analytic derivatives
  k_pair<<<dim3(N1C, BB), 256, 0, stream>>>(UA, VAT, UB, VBT, A_w2, A_b2, B_w2,
                                            B_b2, ligand_pos, target_pos, lvdw,
                                            tvdw, lnm, tnm, inter_ind, hb_c,
                                            hp_c, PART);

  // final reduction -> 34 outputs
  k_final<<<1, 256, 0, stream>>>(PART, rotor, rc_c, (float*)d_out);
}

// Round 5
// 469.984 us; speedup vs baseline: 2.1680x; 1.3114x over previous
//
#include <hip/hip_runtime.h>
#include <math.h>

// ---------------------------------------------------------------------------
// Problem constants (B=8, N1=128, N2=256, D=128, L=3, NH=54)
// Packed row space: rows 0..1023 = ligand (b*128+i), rows 1024..3071 = target
// (1024 + b*256 + j).
// ---------------------------------------------------------------------------
#define BB 8
#define N1C 128
#define N2C 256
#define DC 128
#define NHC 54
#define ROWS_L 1024
#define ROWS_T 2048
#define ROWS_ALL 3072

// ---------------------------------------------------------------------------
// Reductions (wave64)
// ---------------------------------------------------------------------------
__device__ __forceinline__ float wredSum(float v) {
#pragma unroll
  for (int o = 32; o > 0; o >>= 1) v += __shfl_down(v, o);
  return v;
}
__device__ float blockSum(float v) {
  __shared__ float red[9];
  v = wredSum(v);
  int lane = threadIdx.x & 63, wid = threadIdx.x >> 6;
  __syncthreads();
  if (lane == 0) red[wid] = v;
  __syncthreads();
  if (threadIdx.x == 0) {
    float s = 0.f;
    int nw = (blockDim.x + 63) >> 6;
    for (int i = 0; i < nw; ++i) s += red[i];
    red[8] = s;
  }
  __syncthreads();
  return red[8];
}

// ---------------------------------------------------------------------------
// Embedding: H0[r][d] = (r<1024 ? ligand_h[r] : target_h[r-1024]) @ emb_w
// 4 rows/block, 768 blocks.
// ---------------------------------------------------------------------------
__global__ __launch_bounds__(128) void k_emb(const float* __restrict__ LH,
                                             const float* __restrict__ TH,
                                             const float* __restrict__ W,
                                             float* __restrict__ H0) {
  int r0 = blockIdx.x * 4;
  __shared__ float xs[4][NHC];
  for (int t = threadIdx.x; t < 4 * NHC; t += 128) {
    int rr = r0 + t / NHC, c = t % NHC;
    xs[t / NHC][c] = (rr < ROWS_L) ? LH[(long)rr * NHC + c]
                                   : TH[(long)(rr - ROWS_L) * NHC + c];
  }
  __syncthreads();
  int d = threadIdx.x;
  float a0 = 0.f, a1 = 0.f, a2 = 0.f, a3 = 0.f;
#pragma unroll 6
  for (int k = 0; k < NHC; ++k) {
    float wv = W[(long)k * DC + d];
    a0 += xs[0][k] * wv;
    a1 += xs[1][k] * wv;
    a2 += xs[2][k] * wv;
    a3 += xs[3][k] * wv;
  }
  H0[(long)(r0 + 0) * DC + d] = a0;
  H0[(long)(r0 + 1) * DC + d] = a1;
  H0[(long)(r0 + 2) * DC + d] = a2;
  H0[(long)(r0 + 3) * DC + d] = a3;
}

// ---------------------------------------------------------------------------
// Fused GAT weight precompute: WA_l = gat_w_l @ gat_att_l  (and bA_l = b@ATT).
// grid (33, 3): bx<32 -> 4 rows of WA; bx==32 -> bias row.
// ---------------------------------------------------------------------------
__global__ __launch_bounds__(128) void k_wfuse(const float* __restrict__ GWp,
                                               const float* __restrict__ GBp,
                                               const float* __restrict__ ATT,
                                               float* __restrict__ WA,
                                               float* __restrict__ bA) {
  int l = blockIdx.y;
  const float* Wl = GWp + (long)l * DC * DC;
  const float* Al = ATT + (long)l * DC * DC;
  int d = threadIdx.x;
  if (blockIdx.x == 32) {
    float acc = 0.f;
#pragma unroll 8
    for (int m = 0; m < DC; ++m) acc += GBp[l * DC + m] * Al[(long)m * DC + d];
    bA[l * DC + d] = acc;
    return;
  }
  int r0 = blockIdx.x * 4;
  __shared__ float xs[4][DC];
  for (int t = threadIdx.x; t < 4 * DC; t += 128)
    xs[t >> 7][t & 127] = Wl[(long)r0 * DC + t];
  __syncthreads();
  float a0 = 0.f, a1 = 0.f, a2 = 0.f, a3 = 0.f;
#pragma unroll 8
  for (int m = 0; m < DC; ++m) {
    float av = Al[(long)m * DC + d];
    a0 += xs[0][m] * av;
    a1 += xs[1][m] * av;
    a2 += xs[2][m] * av;
    a3 += xs[3][m] * av;
  }
  float* out = WA + (long)l * DC * DC + (long)r0 * DC + d;
  out[0] = a0;
  out[DC] = a1;
  out[2 * DC] = a2;
  out[3 * DC] = a3;
}

// ---------------------------------------------------------------------------
// Dual-head linear (the workhorse): Y1 = X@W1(+b1), Y2 = X@W2(+b2).
// 4 rows/block, 256 threads: tid>>7 selects head, d = tid&127.
// trans=1 stores Yh[b][d][row_in_batch] (rpb rows per batch).
// ---------------------------------------------------------------------------
__global__ __launch_bounds__(256) void k_lin2h(
    const float* __restrict__ X, const float* __restrict__ W1,
    const float* __restrict__ b1, const float* __restrict__ W2,
    const float* __restrict__ b2, float* __restrict__ Y1, float* __restrict__ Y2,
    int rpb, int trans) {
  int r0 = blockIdx.x * 4;
  __shared__ float xs[4][DC];
  int tid = threadIdx.x;
  for (int t = tid; t < 4 * DC; t += 256)
    xs[t >> 7][t & 127] = X[(long)r0 * DC + t];
  __syncthreads();
  int h = tid >> 7, d = tid & 127;
  const float* W = h ? W2 : W1;
  const float* bp = h ? b2 : b1;
  float* Y = h ? Y2 : Y1;
  float a0 = 0.f, a1 = 0.f, a2 = 0.f, a3 = 0.f;
#pragma unroll 16
  for (int k = 0; k < DC; ++k) {
    float wv = W[(long)k * DC + d];
    a0 += xs[0][k] * wv;
    a1 += xs[1][k] * wv;
    a2 += xs[2][k] * wv;
    a3 += xs[3][k] * wv;
  }
  float bv = bp ? bp[d] : 0.f;
  float v[4] = {a0 + bv, a1 + bv, a2 + bv, a3 + bv};
  if (!trans) {
#pragma unroll
    for (int r = 0; r < 4; ++r) Y[(long)(r0 + r) * DC + d] = v[r];
  } else {
    int b = r0 / rpb, rin = r0 - b * rpb;  // 4 | rpb, so same batch
#pragma unroll
    for (int r = 0; r < 4; ++r)
      Y[((long)b * DC + d) * rpb + rin + r] = v[r];
  }
}

// ---------------------------------------------------------------------------
// ea[b,j,k] = e1_j.nt_k + nt_j.e1_k, masked by adjacency at write time.
// 16x16 tile per block.  grid (N/16, N/16, B), block (16,16).
// ---------------------------------------------------------------------------
template <int N>
__global__ __launch_bounds__(256) void k_ea(const float* __restrict__ NTp,
                                            const float* __restrict__ E1p,
                                            const float* __restrict__ ADJ,
                                            float* __restrict__ EAp,
                                            int baseRow) {
  const int D = DC;
  int b = blockIdx.z;
  int j0 = blockIdx.y * 16, k0 = blockIdx.x * 16;
  int tj = threadIdx.y, tk = threadIdx.x;
  __shared__ float e1j[16][17], ntj[16][17], e1k[16][17], ntk[16][17];
  const float* E1b = E1p + (long)(baseRow + b * N) * D;
  const float* NTb = NTp + (long)(baseRow + b * N) * D;
  float acc = 0.f;
  for (int kk = 0; kk < D; kk += 16) {
    e1j[tj][tk] = E1b[(long)(j0 + tj) * D + kk + tk];
    ntj[tj][tk] = NTb[(long)(j0 + tj) * D + kk + tk];
    e1k[tj][tk] = E1b[(long)(k0 + tj) * D + kk + tk];
    ntk[tj][tk] = NTb[(long)(k0 + tj) * D + kk + tk];
    __syncthreads();
#pragma unroll
    for (int t = 0; t < 16; ++t)
      acc += e1j[tj][t] * ntk[tk][t] + ntj[tj][t] * e1k[tk][t];
    __syncthreads();
  }
  long idx = (long)b * N * N + (long)(j0 + tj) * N + k0 + tk;
  float ad = ADJ[idx];
  EAp[idx] = (ad > 1e-6f) ? acc : -9e15f;
}

// ---------------------------------------------------------------------------
// Merged (ligand+target) fused row-softmax + aggregate + gated residual.
// z=0: ligand (N=128, EAL), z=1: target (N=256, EAT).  8 rows/block,
// 512 threads.  Y = g*x + (1-g)*relu(P@NT).
// ---------------------------------------------------------------------------
__global__ __launch_bounds__(512) void k_smagg(
    const float* __restrict__ EAL, const float* __restrict__ EAT,
    const float* __restrict__ NTp, const float* __restrict__ Xp,
    const float* __restrict__ GW, const float* __restrict__ GB,
    float* __restrict__ Y) {
  int z = blockIdx.z;
  int N = z ? N2C : N1C;
  if (blockIdx.x * 8 >= N) return;
  int ls = z ? 8 : 7;
  int baseRow = z ? ROWS_L : 0;
  const float* EA = z ? EAT : EAL;
  int b = blockIdx.y, i0 = blockIdx.x * 8;
  __shared__ float ps[8][N2C + 4];
  __shared__ float col[32][DC + 4];
  __shared__ float red[8][2];
  int tid = threadIdx.x;
  const float* EAb = EA + (long)b * N * N + (long)i0 * N;
  for (int t = tid; t < 8 * N; t += 512)
    ps[t >> ls][t & (N - 1)] = EAb[t];
  __syncthreads();
  {  // softmax: 64 lanes per row
    int r = tid >> 6, l = tid & 63;
    float m = -INFINITY;
    for (int k = l; k < N; k += 64) m = fmaxf(m, ps[r][k]);
#pragma unroll
    for (int o = 32; o > 0; o >>= 1) m = fmaxf(m, __shfl_xor(m, o));
    float s = 0.f;
    for (int k = l; k < N; k += 64) {
      float p = expf(ps[r][k] - m);
      ps[r][k] = p;
      s += p;
    }
#pragma unroll
    for (int o = 32; o > 0; o >>= 1) s += __shfl_xor(s, o);
    float inv = 1.f / s;
    for (int k = l; k < N; k += 64) ps[r][k] *= inv;
  }
  // aggregate: d = tid&127, group ro = tid>>7 handles rows ro and ro+4
  int d = tid & 127, ro = tid >> 7;
  float acc[2] = {0.f, 0.f};
  const float* NTb = NTp + (long)(baseRow + b * N) * DC;
  for (int k0 = 0; k0 < N; k0 += 32) {
    __syncthreads();
    for (int t = tid; t < 32 * DC; t += 512)
      col[t >> 7][t & 127] = NTb[(long)(k0 + (t >> 7)) * DC + (t & 127)];
    __syncthreads();
#pragma unroll 8
    for (int kk = 0; kk < 32; ++kk) {
      float cv = col[kk][d];
      acc[0] = fmaf(ps[ro][k0 + kk], cv, acc[0]);
      acc[1] = fmaf(ps[ro + 4][k0 + kk], cv, acc[1]);
    }
  }
  // fused gate
  float gwd = GW[d], gwo = GW[DC + d];
  float xv[2], ov[2], part[2];
#pragma unroll
  for (int q = 0; q < 2; ++q) {
    int r = ro + 4 * q;
    float o = fmaxf(acc[q], 0.f);
    ov[q] = o;
    float x = Xp[(long)(baseRow + b * N + i0 + r) * DC + d];
    xv[q] = x;
    part[q] = x * gwd + o * gwo;
  }
  int wid = tid >> 6;
#pragma unroll
  for (int q = 0; q < 2; ++q) {
    float v = wredSum(part[q]);
    if ((tid & 63) == 0) red[wid][q] = v;
  }
  __syncthreads();
  float gb = GB[0];
#pragma unroll
  for (int q = 0; q < 2; ++q) {
    int r = ro + 4 * q;
    float s = red[2 * ro][q] + red[2 * ro + 1][q];
    float g = 1.f / (1.f + expf(-(s + gb)));
    Y[(long)(baseRow + b * N + i0 + r) * DC + d] = g * xv[q] + (1.f - g) * ov[q];
  }
}

// adj12 from positions
__global__ void k_adj12(const float* __restrict__ LP, const float* __restrict__ TP,
                        float* __restrict__ AD) {
  long idx = (long)blockIdx.x * blockDim.x + threadIdx.x;
  if (idx >= (long)BB * N1C * N2C) return;
  int j = idx & (N2C - 1);
  long t = idx >> 8;
  int i = (int)(t & (N1C - 1));
  int b = (int)(t >> 7);
  float dx = LP[((long)b * N1C + i) * 3 + 0] - TP[((long)b * N2C + j) * 3 + 0];
  float dy = LP[((long)b * N1C + i) * 3 + 1] - TP[((long)b * N2C + j) * 3 + 1];
  float dz = LP[((long)b * N1C + i) * 3 + 2] - TP[((long)b * N2C + j) * 3 + 2];
  float d = sqrtf(dx * dx + dy * dy + dz * dz + 1e-10f);
  if (d < 0.5f) d = 1e10f;
  AD[idx] = (d <= 5.0f && d > 1e-3f) ? 1.f : 0.f;
}

// ---------------------------------------------------------------------------
// Merged msg kernel: z=0 ligand update (Ni=128,Nj=256), z=1 target update
// (Ni=256,Nj=128, transposed EV access).  msg = relu(t1 + max_j m2_j*ev_ij).
// ---------------------------------------------------------------------------
__global__ __launch_bounds__(256) void k_msg2z(const float* __restrict__ T1,
                                               const float* __restrict__ M2,
                                               const float* __restrict__ EV,
                                               float* __restrict__ MSG) {
  int z = blockIdx.z, b = blockIdx.y;
  int Ni = z ? N2C : N1C, Nj = z ? N1C : N2C;
  int t1off = z ? ROWS_L : 0, m2off = z ? 0 : ROWS_L;
  long ev_is = z ? 1L : (long)N2C, ev_js = z ? (long)N2C : 1L;
  int i0 = blockIdx.x * 8;
  if (i0 >= Ni) return;
  __shared__ float m2s[32][DC];
  __shared__ float evs[8][32];
  int d = threadIdx.x & 127, io = threadIdx.x >> 7;
  float acc[4];
#pragma unroll
  for (int q = 0; q < 4; ++q) acc[q] = -INFINITY;
  const float* M2b = M2 + (long)(m2off + b * Nj) * DC;
  const float* EVb = EV + (long)b * (N1C * N2C);
  for (int j0 = 0; j0 < Nj; j0 += 32) {
    __syncthreads();
    for (int t = threadIdx.x; t < 32 * DC; t += 256)
      m2s[t >> 7][t & 127] = M2b[(long)(j0 + (t >> 7)) * DC + (t & 127)];
    for (int t = threadIdx.x; t < 8 * 32; t += 256)
      evs[t >> 5][t & 31] =
          EVb[(long)(i0 + (t >> 5)) * ev_is + (long)(j0 + (t & 31)) * ev_js];
    __syncthreads();
#pragma unroll 8
    for (int jj = 0; jj < 32; ++jj) {
      float m2v = m2s[jj][d];
#pragma unroll
      for (int q = 0; q < 4; ++q)
        acc[q] = fmaxf(acc[q], m2v * evs[io + 2 * q][jj]);
    }
  }
#pragma unroll
  for (int q = 0; q < 4; ++q) {
    int i = i0 + io + 2 * q;
    long row = t1off + (long)b * Ni + i;
    MSG[row * DC + d] = fmaxf(T1[row * DC + d] + acc[q], 0.f);
  }
}

// ---------------------------------------------------------------------------
// Fused GRU over all 3072 rows: gi = msg@WihT+bih, gh = h@WhhT+bhh, combine.
// ---------------------------------------------------------------------------
__global__ __launch_bounds__(384) void k_gruf(
    const float* __restrict__ MSGp, const float* __restrict__ Hp,
    const float* __restrict__ WihT, const float* __restrict__ WhhT,
    const float* __restrict__ bih, const float* __restrict__ bhh,
    float* __restrict__ Y) {
  const int D = DC;
  int r0 = blockIdx.x * 8;
  __shared__ float xs[8][DC], hs[8][DC];
  __shared__ float gis[8][384], ghs[8][384];
  for (int t = threadIdx.x; t < 8 * DC; t += 384) {
    int r = t >> 7, c = t & 127;
    xs[r][c] = MSGp[(long)(r0 + r) * D + c];
    hs[r][c] = Hp[(long)(r0 + r) * D + c];
  }
  __syncthreads();
  int dd = threadIdx.x;
  float ai[8], ah[8];
#pragma unroll
  for (int r = 0; r < 8; ++r) { ai[r] = 0.f; ah[r] = 0.f; }
#pragma unroll 8
  for (int k = 0; k < DC; ++k) {
    float wi = WihT[(long)k * 384 + dd];
    float wh = WhhT[(long)k * 384 + dd];
#pragma unroll
    for (int r = 0; r < 8; ++r) {
      ai[r] += xs[r][k] * wi;
      ah[r] += hs[r][k] * wh;
    }
  }
  float bi = bih[dd], bh = bhh[dd];
#pragma unroll
  for (int r = 0; r < 8; ++r) {
    gis[r][dd] = ai[r] + bi;
    ghs[r][dd] = ah[r] + bh;
  }
  __syncthreads();
  for (int t = threadIdx.x; t < 8 * DC; t += 384) {
    int r = t >> 7, d = t & 127;
    float ir = gis[r][d], iz = gis[r][d + 128], inn = gis[r][d + 256];
    float hr = ghs[r][d], hz = ghs[r][d + 128], hn = ghs[r][d + 256];
    float rg = 1.f / (1.f + expf(-(ir + hr)));
    float zg = 1.f / (1.f + expf(-(iz + hz)));
    float ng = tanhf(inn + rg * hn);
    Y[(long)(r0 + r) * D + d] = (1.f - zg) * ng + zg * hs[r][d];
  }
}

// transpose all 6 GRU weight matrices [384][128] -> [128][384] in one go
__global__ void k_tall(const float* __restrict__ IH, const float* __restrict__ HH,
                       float* __restrict__ GIHT, float* __restrict__ GHHT) {
  long idx = (long)blockIdx.x * 256 + threadIdx.x;
  if (idx >= 6L * 49152) return;
  int a = (int)(idx / 49152);
  int rem = (int)(idx % 49152);
  int l = a >> 1, whh = a & 1;
  int c = rem / 384, rr = rem % 384;
  const float* src = (whh ? HH : IH) + (long)l * 49152;
  float* dst = (whh ? GHHT : GIHT) + (long)l * 49152;
  dst[(long)c * 384 + rr] = src[(long)rr * 128 + c];
}

// ---------------------------------------------------------------------------
// Pairwise physics + analytic grad/Hessian partials (verified).
// ---------------------------------------------------------------------------
__global__ __launch_bounds__(256) void k_pair(
    const float* __restrict__ UA, const float* __restrict__ VAT,
    const float* __restrict__ UB, const float* __restrict__ VBT,
    const float* __restrict__ AW2, const float* __restrict__ AB2,
    const float* __restrict__ BW2, const float* __restrict__ BB2,
    const float* __restrict__ LP, const float* __restrict__ TP,
    const float* __restrict__ LVDW, const float* __restrict__ TVDW,
    const float* __restrict__ LNM, const float* __restrict__ TNM,
    const float* __restrict__ II, const float* __restrict__ HBC,
    const float* __restrict__ HPC, float* __restrict__ PART) {
  const int D = DC, N1 = N1C, N2 = N2C;
  int i = blockIdx.x, b = blockIdx.y, j = threadIdx.x;
  __shared__ float ua[128], ub[128], wa2[128], wb2[128];
  if (j < 128) {
    long rb = ((long)b * N1 + i) * D + j;
    ua[j] = UA[rb];
    ub[j] = UB[rb];
    wa2[j] = AW2[j];
    wb2[j] = BW2[j];
  }
  __syncthreads();
  const float* vat = VAT + (long)b * D * N2;
  const float* vbt = VBT + (long)b * D * N2;
  float dotA = 0.f, dotB = 0.f;
#pragma unroll 8
  for (int d = 0; d < D; ++d) {
    dotA += fmaxf(ua[d] + vat[(long)d * N2 + j], 0.f) * wa2[d];
    dotB += fmaxf(ub[d] + vbt[(long)d * N2 + j], 0.f) * wb2[d];
  }
  float A_raw = 1.f / (1.f + expf(-(dotA + AB2[0])));
  float A_vdw = A_raw * (0.0356f - 0.0178f) + 0.0178f;
  float B_raw = tanhf(dotB + BB2[0]) * 0.2f;

  float lx = LP[((long)b * N1 + i) * 3 + 0];
  float ly = LP[((long)b * N1 + i) * 3 + 1];
  float lz = LP[((long)b * N1 + i) * 3 + 2];
  float tx = TP[((long)b * N2 + j) * 3 + 0];
  float ty = TP[((long)b * N2 + j) * 3 + 1];
  float tz = TP[((long)b * N2 + j) * 3 + 2];
  float dx = lx - tx, dy = ly - ty, dz = lz - tz;
  float s2 = dx * dx + dy * dy + dz * dz + 1e-10f;
  float draw = sqrtf(s2);
  bool clamped = draw < 0.5f;
  float dmv = clamped ? 1e10f : draw;

  float dm0 = LVDW[b * N1 + i] + TVDW[b * N2 + j] + B_raw;
  float dm0c = (dm0 < 1e-4f) ? 1.f : dm0;
  float valid = LNM[b * N1 + i] * TNM[b * N2 + j];

  float rr = dm0c / dmv;
  float r2 = rr * rr, r6 = r2 * r2 * r2;
  float fv = r6 * r6 - 2.f * r6;
  float evdw = A_vdw * (fminf(fv, 100.f) * valid);

  float dmd = dmv - dm0;
  long ii0 = ((long)b * 3) * N1 * N2 + (long)i * N2 + j;
  float I0 = II[ii0];
  float I1 = II[ii0 + (long)N1 * N2];
  float I2 = II[ii0 + 2L * N1 * N2];
  float hb2 = HBC[0] * HBC[0], hp2 = HPC[0] * HPC[0];
  float u0 = dmd * I0 / (-0.7f);
  float u1 = dmd * I1 / (-0.7f);
  float vv = (1.5f - dmd) * I2;
  float ehb = fminf(fmaxf(u0, 0.f), 1.f) * (-hb2);
  float emt = fminf(fmaxf(u1, 0.f), 1.f) * (-hb2);
  float ehp = fminf(fmaxf(vv, 0.f), 1.f) * (-hp2);

  float gx = 0.f, gy = 0.f, gz = 0.f, d2t = 0.f;
  if (!clamped) {
    float Ep = 0.f, Epp = 0.f;
    if (fv < 100.f) {
      float c = A_vdw * valid;
      Ep += c * (-12.f) * r6 * (r6 - 1.f) / draw;
      Epp += c * r6 * (156.f * r6 - 84.f) / s2;
    }
    if (u0 > 0.f && u0 < 1.f) Ep += hb2 * I0 * (1.f / 0.7f);
    if (u1 > 0.f && u1 < 1.f) Ep += hb2 * I1 * (1.f / 0.7f);
    if (vv > 0.f && vv < 1.f) Ep += hp2 * I2;
    float invd = 1.f / draw;
    gx = Ep * dx * invd;
    gy = Ep * dy * invd;
    gz = Ep * dz * invd;
    float T = dx + dy + dz;
    float tt = T * T / s2;
    d2t = Epp * tt + Ep * (3.f - tt) * invd;
  }

  float o0 = blockSum(evdw);
  float o1 = blockSum(ehb);
  float o2 = blockSum(emt);
  float o3 = blockSum(ehp);
  float o4 = blockSum(gx);
  float o5 = blockSum(gy);
  float o6 = blockSum(gz);
  float o7 = blockSum(d2t);
  if (j == 0) {
    float* p = PART + ((long)b * N1 + i) * 8;
    p[0] = o0; p[1] = o1; p[2] = o2; p[3] = o3;
    p[4] = o4; p[5] = o5; p[6] = o6; p[7] = o7;
  }
}

// final deterministic reduction + output assembly (34 floats)
__global__ void k_final(const float* __restrict__ PART, const float* __restrict__ ROT,
                        const float* __restrict__ RC, float* __restrict__ OUT) {
  const int N1 = N1C;
  __shared__ float s[8][8];
  int t = threadIdx.x;
  if (t < 64) {
    int b = t >> 3, k1 = t & 7;
    float acc = 0.f;
    for (int i = 0; i < N1; ++i) acc += PART[((long)b * N1 + i) * 8 + k1];
    s[b][k1] = acc;
  }
  __syncthreads();
  if (t == 0) {
    float rcc = RC[0] * RC[0];
    float der1 = 0.f, der2 = 0.f;
    for (int b = 0; b < 8; ++b) {
      float w = 1.f / (1.f + rcc * ROT[b]);
      OUT[b * 4 + 0] = s[b][0] * w;
      OUT[b * 4 + 1] = s[b][1] * w;
      OUT[b * 4 + 2] = s[b][2] * w;
      OUT[b * 4 + 3] = s[b][3] * w;
      for (int c = 0; c < 3; ++c) {
        float S = s[b][4 + c] * w;
        der1 += S * S;
      }
      der2 += s[b][7] * w;
    }
    OUT[32] = der1 / 24.f;
    OUT[33] = -der2 / 8.f;
  }
}

// ---------------------------------------------------------------------------
// Host-side orchestration
// ---------------------------------------------------------------------------
extern "C" void kernel_launch(void* const* d_in, const int* in_sizes, int n_in,
                              void* d_out, int out_size, void* d_ws, size_t ws_size,
                              hipStream_t stream) {
  (void)in_sizes; (void)n_in; (void)out_size; (void)ws_size;
  const int D = DC;

  const float* ligand_h   = (const float*)d_in[0];
  const float* ligand_adj = (const float*)d_in[1];
  const float* target_h   = (const float*)d_in[2];
  const float* target_adj = (const float*)d_in[3];
  const float* inter_ind  = (const float*)d_in[4];
  const float* ligand_pos = (const float*)d_in[5];
  const float* target_pos = (const float*)d_in[6];
  const float* rotor      = (const float*)d_in[7];
  const float* lvdw       = (const float*)d_in[8];
  const float* tvdw       = (const float*)d_in[9];
  const float* lnm        = (const float*)d_in[12];
  const float* tnm        = (const float*)d_in[13];
  const float* emb_w      = (const float*)d_in[14];
  const float* gat_w      = (const float*)d_in[15];
  const float* gat_b      = (const float*)d_in[16];
  const float* gat_att    = (const float*)d_in[17];
  const float* gat_gate_w = (const float*)d_in[18];
  const float* gat_gate_b = (const float*)d_in[19];
  const float* int_wt_w   = (const float*)d_in[20];
  const float* int_wt_b   = (const float*)d_in[21];
  const float* int_mt_w   = (const float*)d_in[22];
  const float* int_mt_b   = (const float*)d_in[23];
  const float* gru_w_ih   = (const float*)d_in[24];
  const float* gru_w_hh   = (const float*)d_in[25];
  const float* gru_b_ih   = (const float*)d_in[26];
  const float* gru_b_hh   = (const float*)d_in[27];
  const float* A_w1       = (const float*)d_in[28];
  const float* A_b1       = (const float*)d_in[29];
  const float* A_w2       = (const float*)d_in[30];
  const float* A_b2       = (const float*)d_in[31];
  const float* B_w1       = (const float*)d_in[32];
  const float* B_b1       = (const float*)d_in[33];
  const float* B_w2       = (const float*)d_in[34];
  const float* B_b2       = (const float*)d_in[35];
  const float* hb_c       = (const float*)d_in[36];
  const float* hp_c       = (const float*)d_in[37];
  const float* rc_c       = (const float*)d_in[38];

  // workspace carve (floats)
  float* w = (float*)d_ws;
  auto take = [&](size_t n) { float* p = w; w += n; return p; };
  float* H0    = take((size_t)ROWS_ALL * DC);   // 393216
  float* H1    = take((size_t)ROWS_ALL * DC);
  float* NT    = take((size_t)ROWS_ALL * DC);
  float* E1    = take((size_t)ROWS_ALL * DC);
  float* EAL   = take((size_t)BB * N1C * N1C);  // 131072
  float* EAT   = take((size_t)BB * N2C * N2C);  // 524288
  float* ADJ12 = take((size_t)BB * N1C * N2C);  // 262144
  float* WA    = take((size_t)3 * DC * DC);     // 49152
  float* bA    = take((size_t)3 * DC);
  float* GIHT  = take((size_t)3 * DC * 384);    // 147456
  float* GHHT  = take((size_t)3 * DC * 384);
  float* PART  = take((size_t)BB * N1C * 8);
  // phase-disjoint aliases
  float* T1  = NT;
  float* M2  = E1;
  float* MSG = EAT;           // 393216 <= 524288
  float* UA  = EAL;           // 131072
  float* UB  = EAT;           // 131072 (front of EAT)
  float* VAT = NT;            // 262144 <= 393216
  float* VBT = E1;            // 262144

  // geometry adjacency + embedding + fused GAT weights
  k_adj12<<<(BB * N1C * N2C + 255) / 256, 256, 0, stream>>>(ligand_pos,
                                                            target_pos, ADJ12);
  k_emb<<<ROWS_ALL / 4, 128, 0, stream>>>(ligand_h, target_h, emb_w, H0);
  k_wfuse<<<dim3(33, 3), 128, 0, stream>>>(gat_w, gat_b, gat_att, WA, bA);

  float *cur = H0, *alt = H1;

  // GAT stack (3 layers)
  for (int l = 0; l < 3; ++l) {
    k_lin2h<<<ROWS_ALL / 4, 256, 0, stream>>>(
        cur, gat_w + (size_t)l * D * D, gat_b + l * D, WA + (size_t)l * D * D,
        bA + l * D, NT, E1, 1, 0);
    k_ea<N1C><<<dim3(N1C / 16, N1C / 16, BB), dim3(16, 16), 0, stream>>>(
        NT, E1, ligand_adj, EAL, 0);
    k_ea<N2C><<<dim3(N2C / 16, N2C / 16, BB), dim3(16, 16), 0, stream>>>(
        NT, E1, target_adj, EAT, ROWS_L);
    k_smagg<<<dim3(N2C / 8, BB, 2), 512, 0, stream>>>(
        EAL, EAT, NT, cur, gat_gate_w + l * 2 * D, gat_gate_b + l, alt);
    float* t = cur; cur = alt; alt = t;
  }

  // GRU weight transposes (single dispatch)
  k_tall<<<(6 * 49152 + 255) / 256, 256, 0, stream>>>(gru_w_ih, gru_w_hh, GIHT,
                                                      GHHT);

  // interaction layers (both directions per dispatch; both use OLD h)
  for (int l = 0; l < 3; ++l) {
    k_lin2h<<<ROWS_ALL / 4, 256, 0, stream>>>(
        cur, int_wt_w + (size_t)l * D * D, int_wt_b + l * D,
        int_mt_w + (size_t)l * D * D, int_mt_b + l * D, T1, M2, 1, 0);
    k_msg2z<<<dim3(N2C / 8, BB, 2), 256, 0, stream>>>(T1, M2, ADJ12, MSG);
    k_gruf<<<ROWS_ALL / 8, 384, 0, stream>>>(MSG, cur, GIHT + (size_t)l * D * 384,
                                             GHHT + (size_t)l * D * 384,
                                             gru_b_ih + l * 384,
                                             gru_b_hh + l * 384, alt);
    float* t = cur; cur = alt; alt = t;
  }

  // pairwise feature precompute (U normal layout, V transposed [b][d][j])
  k_lin2h<<<ROWS_L / 4, 256, 0, stream>>>(cur, A_w1, A_b1, B_w1, B_b1, UA, UB,
                                          1, 0);
  k_lin2h<<<ROWS_T / 4, 256, 0, stream>>>(cur + (size_t)ROWS_L * DC,
                                          A_w1 + D * D, nullptr, B_w1 + D * D,
                                          nullptr, VAT, VBT, N2C, 1);

  // pairwise physics + analytic derivatives
  k_pair<<<dim3(N1C, BB), 256, 0, stream>>>(UA, VAT, UB, VBT, A_w2, A_b2, B_w2,
                                            B_b2, ligand_pos, target_pos, lvdw,
                                            tvdw, lnm, tnm, inter_ind, hb_c,
                                            hp_c, PART);

  // final reduction -> 34 outputs
  k_final<<<1, 256, 0, stream>>>(PART, rotor, rc_c, (float*)d_out);
}

// Round 6
// 374.027 us; speedup vs baseline: 2.7242x; 1.2566x over previous
//
#include <hip/hip_runtime.h>
#include <math.h>

// ---------------------------------------------------------------------------
// Problem constants (B=8, N1=128, N2=256, D=128, L=3, NH=54)
// Packed row space: rows 0..1023 = ligand (b*128+i), rows 1024..3071 = target
// (1024 + b*256 + j).
// ---------------------------------------------------------------------------
#define BB 8
#define N1C 128
#define N2C 256
#define DC 128
#define NHC 54
#define ROWS_L 1024
#define ROWS_T 2048
#define ROWS_ALL 3072

// ---------------------------------------------------------------------------
// Reductions (wave64)
// ---------------------------------------------------------------------------
__device__ __forceinline__ float wredSum(float v) {
#pragma unroll
  for (int o = 32; o > 0; o >>= 1) v += __shfl_down(v, o);
  return v;
}
__device__ float blockSum(float v) {
  __shared__ float red[9];
  v = wredSum(v);
  int lane = threadIdx.x & 63, wid = threadIdx.x >> 6;
  __syncthreads();
  if (lane == 0) red[wid] = v;
  __syncthreads();
  if (threadIdx.x == 0) {
    float s = 0.f;
    int nw = (blockDim.x + 63) >> 6;
    for (int i = 0; i < nw; ++i) s += red[i];
    red[8] = s;
  }
  __syncthreads();
  return red[8];
}

// ---------------------------------------------------------------------------
// Embedding: H0[r][d] = (r<1024 ? ligand_h[r] : target_h[r-1024]) @ emb_w
// 4 rows/block, 768 blocks.
// ---------------------------------------------------------------------------
__global__ __launch_bounds__(128) void k_emb(const float* __restrict__ LH,
                                             const float* __restrict__ TH,
                                             const float* __restrict__ W,
                                             float* __restrict__ H0) {
  int r0 = blockIdx.x * 4;
  __shared__ float xs[4][NHC];
  for (int t = threadIdx.x; t < 4 * NHC; t += 128) {
    int rr = r0 + t / NHC, c = t % NHC;
    xs[t / NHC][c] = (rr < ROWS_L) ? LH[(long)rr * NHC + c]
                                   : TH[(long)(rr - ROWS_L) * NHC + c];
  }
  __syncthreads();
  int d = threadIdx.x;
  float a0 = 0.f, a1 = 0.f, a2 = 0.f, a3 = 0.f;
#pragma unroll 6
  for (int k = 0; k < NHC; ++k) {
    float wv = W[(long)k * DC + d];
    a0 += xs[0][k] * wv;
    a1 += xs[1][k] * wv;
    a2 += xs[2][k] * wv;
    a3 += xs[3][k] * wv;
  }
  H0[(long)(r0 + 0) * DC + d] = a0;
  H0[(long)(r0 + 1) * DC + d] = a1;
  H0[(long)(r0 + 2) * DC + d] = a2;
  H0[(long)(r0 + 3) * DC + d] = a3;
}

// ---------------------------------------------------------------------------
// Fused GAT weight precompute: WA_l = gat_w_l @ gat_att_l  (and bA_l = b@ATT).
// grid (33, 3): bx<32 -> 4 rows of WA; bx==32 -> bias row.
// ---------------------------------------------------------------------------
__global__ __launch_bounds__(128) void k_wfuse(const float* __restrict__ GWp,
                                               const float* __restrict__ GBp,
                                               const float* __restrict__ ATT,
                                               float* __restrict__ WA,
                                               float* __restrict__ bA) {
  int l = blockIdx.y;
  const float* Wl = GWp + (long)l * DC * DC;
  const float* Al = ATT + (long)l * DC * DC;
  int d = threadIdx.x;
  if (blockIdx.x == 32) {
    float acc = 0.f;
#pragma unroll 8
    for (int m = 0; m < DC; ++m) acc += GBp[l * DC + m] * Al[(long)m * DC + d];
    bA[l * DC + d] = acc;
    return;
  }
  int r0 = blockIdx.x * 4;
  __shared__ float xs[4][DC];
  for (int t = threadIdx.x; t < 4 * DC; t += 128)
    xs[t >> 7][t & 127] = Wl[(long)r0 * DC + t];
  __syncthreads();
  float a0 = 0.f, a1 = 0.f, a2 = 0.f, a3 = 0.f;
#pragma unroll 8
  for (int m = 0; m < DC; ++m) {
    float av = Al[(long)m * DC + d];
    a0 += xs[0][m] * av;
    a1 += xs[1][m] * av;
    a2 += xs[2][m] * av;
    a3 += xs[3][m] * av;
  }
  float* out = WA + (long)l * DC * DC + (long)r0 * DC + d;
  out[0] = a0;
  out[DC] = a1;
  out[2 * DC] = a2;
  out[3 * DC] = a3;
}

// ---------------------------------------------------------------------------
// Dual-head linear (the workhorse): Y1 = X@W1(+b1), Y2 = X@W2(+b2).
// 4 rows/block, 256 threads: tid>>7 selects head, d = tid&127.
// trans=1 stores Yh[b][d][row_in_batch] (rpb rows per batch).
// ---------------------------------------------------------------------------
__global__ __launch_bounds__(256) void k_lin2h(
    const float* __restrict__ X, const float* __restrict__ W1,
    const float* __restrict__ b1, const float* __restrict__ W2,
    const float* __restrict__ b2, float* __restrict__ Y1, float* __restrict__ Y2,
    int rpb, int trans) {
  int r0 = blockIdx.x * 4;
  __shared__ float xs[4][DC];
  int tid = threadIdx.x;
  for (int t = tid; t < 4 * DC; t += 256)
    xs[t >> 7][t & 127] = X[(long)r0 * DC + t];
  __syncthreads();
  int h = tid >> 7, d = tid & 127;
  const float* W = h ? W2 : W1;
  const float* bp = h ? b2 : b1;
  float* Y = h ? Y2 : Y1;
  float a0 = 0.f, a1 = 0.f, a2 = 0.f, a3 = 0.f;
#pragma unroll 16
  for (int k = 0; k < DC; ++k) {
    float wv = W[(long)k * DC + d];
    a0 += xs[0][k] * wv;
    a1 += xs[1][k] * wv;
    a2 += xs[2][k] * wv;
    a3 += xs[3][k] * wv;
  }
  float bv = bp ? bp[d] : 0.f;
  float v[4] = {a0 + bv, a1 + bv, a2 + bv, a3 + bv};
  if (!trans) {
#pragma unroll
    for (int r = 0; r < 4; ++r) Y[(long)(r0 + r) * DC + d] = v[r];
  } else {
    int b = r0 / rpb, rin = r0 - b * rpb;  // 4 | rpb, so same batch
#pragma unroll
    for (int r = 0; r < 4; ++r)
      Y[((long)b * DC + d) * rpb + rin + r] = v[r];
  }
}

// ---------------------------------------------------------------------------
// ea[b,j,k] = e1_j.nt_k + nt_j.e1_k, masked by adjacency at write time.
// 16x16 tile per block.  grid (N/16, N/16, B), block (16,16).
// ---------------------------------------------------------------------------
template <int N>
__global__ __launch_bounds__(256) void k_ea(const float* __restrict__ NTp,
                                            const float* __restrict__ E1p,
                                            const float* __restrict__ ADJ,
                                            float* __restrict__ EAp,
                                            int baseRow) {
  const int D = DC;
  int b = blockIdx.z;
  int j0 = blockIdx.y * 16, k0 = blockIdx.x * 16;
  int tj = threadIdx.y, tk = threadIdx.x;
  __shared__ float e1j[16][17], ntj[16][17], e1k[16][17], ntk[16][17];
  const float* E1b = E1p + (long)(baseRow + b * N) * D;
  const float* NTb = NTp + (long)(baseRow + b * N) * D;
  float acc = 0.f;
  for (int kk = 0; kk < D; kk += 16) {
    e1j[tj][tk] = E1b[(long)(j0 + tj) * D + kk + tk];
    ntj[tj][tk] = NTb[(long)(j0 + tj) * D + kk + tk];
    e1k[tj][tk] = E1b[(long)(k0 + tj) * D + kk + tk];
    ntk[tj][tk] = NTb[(long)(k0 + tj) * D + kk + tk];
    __syncthreads();
#pragma unroll
    for (int t = 0; t < 16; ++t)
      acc += e1j[tj][t] * ntk[tk][t] + ntj[tj][t] * e1k[tk][t];
    __syncthreads();
  }
  long idx = (long)b * N * N + (long)(j0 + tj) * N + k0 + tk;
  float ad = ADJ[idx];
  EAp[idx] = (ad > 1e-6f) ? acc : -9e15f;
}

// ---------------------------------------------------------------------------
// Merged (ligand+target) fused row-softmax + aggregate + gated residual.
// z=0: ligand (N=128, EAL), z=1: target (N=256, EAT).  8 rows/block,
// 512 threads.  Y = g*x + (1-g)*relu(P@NT).
// ---------------------------------------------------------------------------
__global__ __launch_bounds__(512) void k_smagg(
    const float* __restrict__ EAL, const float* __restrict__ EAT,
    const float* __restrict__ NTp, const float* __restrict__ Xp,
    const float* __restrict__ GW, const float* __restrict__ GB,
    float* __restrict__ Y) {
  int z = blockIdx.z;
  int N = z ? N2C : N1C;
  if (blockIdx.x * 8 >= N) return;
  int ls = z ? 8 : 7;
  int baseRow = z ? ROWS_L : 0;
  const float* EA = z ? EAT : EAL;
  int b = blockIdx.y, i0 = blockIdx.x * 8;
  __shared__ float ps[8][N2C + 4];
  __shared__ float col[32][DC + 4];
  __shared__ float red[8][2];
  int tid = threadIdx.x;
  const float* EAb = EA + (long)b * N * N + (long)i0 * N;
  for (int t = tid; t < 8 * N; t += 512)
    ps[t >> ls][t & (N - 1)] = EAb[t];
  __syncthreads();
  {  // softmax: 64 lanes per row
    int r = tid >> 6, l = tid & 63;
    float m = -INFINITY;
    for (int k = l; k < N; k += 64) m = fmaxf(m, ps[r][k]);
#pragma unroll
    for (int o = 32; o > 0; o >>= 1) m = fmaxf(m, __shfl_xor(m, o));
    float s = 0.f;
    for (int k = l; k < N; k += 64) {
      float p = expf(ps[r][k] - m);
      ps[r][k] = p;
      s += p;
    }
#pragma unroll
    for (int o = 32; o > 0; o >>= 1) s += __shfl_xor(s, o);
    float inv = 1.f / s;
    for (int k = l; k < N; k += 64) ps[r][k] *= inv;
  }
  // aggregate: d = tid&127, group ro = tid>>7 handles rows ro and ro+4
  int d = tid & 127, ro = tid >> 7;
  float acc[2] = {0.f, 0.f};
  const float* NTb = NTp + (long)(baseRow + b * N) * DC;
  for (int k0 = 0; k0 < N; k0 += 32) {
    __syncthreads();
    for (int t = tid; t < 32 * DC; t += 512)
      col[t >> 7][t & 127] = NTb[(long)(k0 + (t >> 7)) * DC + (t & 127)];
    __syncthreads();
#pragma unroll 8
    for (int kk = 0; kk < 32; ++kk) {
      float cv = col[kk][d];
      acc[0] = fmaf(ps[ro][k0 + kk], cv, acc[0]);
      acc[1] = fmaf(ps[ro + 4][k0 + kk], cv, acc[1]);
    }
  }
  // fused gate
  float gwd = GW[d], gwo = GW[DC + d];
  float xv[2], ov[2], part[2];
#pragma unroll
  for (int q = 0; q < 2; ++q) {
    int r = ro + 4 * q;
    float o = fmaxf(acc[q], 0.f);
    ov[q] = o;
    float x = Xp[(long)(baseRow + b * N + i0 + r) * DC + d];
    xv[q] = x;
    part[q] = x * gwd + o * gwo;
  }
  int wid = tid >> 6;
#pragma unroll
  for (int q = 0; q < 2; ++q) {
    float v = wredSum(part[q]);
    if ((tid & 63) == 0) red[wid][q] = v;
  }
  __syncthreads();
  float gb = GB[0];
#pragma unroll
  for (int q = 0; q < 2; ++q) {
    int r = ro + 4 * q;
    float s = red[2 * ro][q] + red[2 * ro + 1][q];
    float g = 1.f / (1.f + expf(-(s + gb)));
    Y[(long)(baseRow + b * N + i0 + r) * DC + d] = g * xv[q] + (1.f - g) * ov[q];
  }
}

// adj12 from positions
__global__ void k_adj12(const float* __restrict__ LP, const float* __restrict__ TP,
                        float* __restrict__ AD) {
  long idx = (long)blockIdx.x * blockDim.x + threadIdx.x;
  if (idx >= (long)BB * N1C * N2C) return;
  int j = idx & (N2C - 1);
  long t = idx >> 8;
  int i = (int)(t & (N1C - 1));
  int b = (int)(t >> 7);
  float dx = LP[((long)b * N1C + i) * 3 + 0] - TP[((long)b * N2C + j) * 3 + 0];
  float dy = LP[((long)b * N1C + i) * 3 + 1] - TP[((long)b * N2C + j) * 3 + 1];
  float dz = LP[((long)b * N1C + i) * 3 + 2] - TP[((long)b * N2C + j) * 3 + 2];
  float d = sqrtf(dx * dx + dy * dy + dz * dz + 1e-10f);
  if (d < 0.5f) d = 1e10f;
  AD[idx] = (d <= 5.0f && d > 1e-3f) ? 1.f : 0.f;
}

// ---------------------------------------------------------------------------
// Merged msg kernel: z=0 ligand update (Ni=128,Nj=256), z=1 target update
// (Ni=256,Nj=128, transposed EV access).  msg = relu(t1 + max_j m2_j*ev_ij).
// ---------------------------------------------------------------------------
__global__ __launch_bounds__(256) void k_msg2z(const float* __restrict__ T1,
                                               const float* __restrict__ M2,
                                               const float* __restrict__ EV,
                                               float* __restrict__ MSG) {
  int z = blockIdx.z, b = blockIdx.y;
  int Ni = z ? N2C : N1C, Nj = z ? N1C : N2C;
  int t1off = z ? ROWS_L : 0, m2off = z ? 0 : ROWS_L;
  long ev_is = z ? 1L : (long)N2C, ev_js = z ? (long)N2C : 1L;
  int i0 = blockIdx.x * 8;
  if (i0 >= Ni) return;
  __shared__ float m2s[32][DC];
  __shared__ float evs[8][32];
  int d = threadIdx.x & 127, io = threadIdx.x >> 7;
  float acc[4];
#pragma unroll
  for (int q = 0; q < 4; ++q) acc[q] = -INFINITY;
  const float* M2b = M2 + (long)(m2off + b * Nj) * DC;
  const float* EVb = EV + (long)b * (N1C * N2C);
  for (int j0 = 0; j0 < Nj; j0 += 32) {
    __syncthreads();
    for (int t = threadIdx.x; t < 32 * DC; t += 256)
      m2s[t >> 7][t & 127] = M2b[(long)(j0 + (t >> 7)) * DC + (t & 127)];
    for (int t = threadIdx.x; t < 8 * 32; t += 256)
      evs[t >> 5][t & 31] =
          EVb[(long)(i0 + (t >> 5)) * ev_is + (long)(j0 + (t & 31)) * ev_js];
    __syncthreads();
#pragma unroll 8
    for (int jj = 0; jj < 32; ++jj) {
      float m2v = m2s[jj][d];
#pragma unroll
      for (int q = 0; q < 4; ++q)
        acc[q] = fmaxf(acc[q], m2v * evs[io + 2 * q][jj]);
    }
  }
#pragma unroll
  for (int q = 0; q < 4; ++q) {
    int i = i0 + io + 2 * q;
    long row = t1off + (long)b * Ni + i;
    MSG[row * DC + d] = fmaxf(T1[row * DC + d] + acc[q], 0.f);
  }
}

// ---------------------------------------------------------------------------
// Fused GRU, 4 rows/block (768 blocks), 384 threads.
// X/H staged TRANSPOSED in LDS so the K-loop reads one ds_read_b128 per
// operand per k (instead of 8 scalar broadcasts).  gi/gh round-trip via LDS.
// ---------------------------------------------------------------------------
__global__ __launch_bounds__(384) void k_gruf(
    const float* __restrict__ MSGp, const float* __restrict__ Hp,
    const float* __restrict__ WihT, const float* __restrict__ WhhT,
    const float* __restrict__ bih, const float* __restrict__ bhh,
    float* __restrict__ Y) {
  const int D = DC;
  int r0 = blockIdx.x * 4;
  __shared__ float xs_t[DC][4], hs_t[DC][4];
  __shared__ float gis[4][384], ghs[4][384];
  int tid = threadIdx.x;
  for (int t = tid; t < 4 * DC; t += 384) {
    int r = t >> 7, c = t & 127;
    xs_t[c][r] = MSGp[(long)(r0 + r) * D + c];
    hs_t[c][r] = Hp[(long)(r0 + r) * D + c];
  }
  __syncthreads();
  int dd = tid;  // 0..383
  float ai[4] = {0.f, 0.f, 0.f, 0.f}, ah[4] = {0.f, 0.f, 0.f, 0.f};
#pragma unroll 8
  for (int k = 0; k < DC; ++k) {
    float4 xv = *reinterpret_cast<const float4*>(&xs_t[k][0]);
    float4 hv = *reinterpret_cast<const float4*>(&hs_t[k][0]);
    float wi = WihT[(long)k * 384 + dd];
    float wh = WhhT[(long)k * 384 + dd];
    ai[0] = fmaf(xv.x, wi, ai[0]);
    ai[1] = fmaf(xv.y, wi, ai[1]);
    ai[2] = fmaf(xv.z, wi, ai[2]);
    ai[3] = fmaf(xv.w, wi, ai[3]);
    ah[0] = fmaf(hv.x, wh, ah[0]);
    ah[1] = fmaf(hv.y, wh, ah[1]);
    ah[2] = fmaf(hv.z, wh, ah[2]);
    ah[3] = fmaf(hv.w, wh, ah[3]);
  }
  float bi = bih[dd], bh = bhh[dd];
#pragma unroll
  for (int r = 0; r < 4; ++r) {
    gis[r][dd] = ai[r] + bi;
    ghs[r][dd] = ah[r] + bh;
  }
  __syncthreads();
  for (int t = tid; t < 4 * DC; t += 384) {
    int r = t >> 7, d = t & 127;
    float ir = gis[r][d], iz = gis[r][d + 128], inn = gis[r][d + 256];
    float hr = ghs[r][d], hz = ghs[r][d + 128], hn = ghs[r][d + 256];
    float rg = 1.f / (1.f + expf(-(ir + hr)));
    float zg = 1.f / (1.f + expf(-(iz + hz)));
    float ng = tanhf(inn + rg * hn);
    Y[(long)(r0 + r) * D + d] = (1.f - zg) * ng + zg * hs_t[d][r];
  }
}

// transpose all 6 GRU weight matrices [384][128] -> [128][384] in one go
__global__ void k_tall(const float* __restrict__ IH, const float* __restrict__ HH,
                       float* __restrict__ GIHT, float* __restrict__ GHHT) {
  long idx = (long)blockIdx.x * 256 + threadIdx.x;
  if (idx >= 6L * 49152) return;
  int a = (int)(idx / 49152);
  int rem = (int)(idx % 49152);
  int l = a >> 1, whh = a & 1;
  int c = rem / 384, rr = rem % 384;
  const float* src = (whh ? HH : IH) + (long)l * 49152;
  float* dst = (whh ? GHHT : GIHT) + (long)l * 49152;
  dst[(long)c * 384 + rr] = src[(long)rr * 128 + c];
}

// ---------------------------------------------------------------------------
// Pairwise physics + analytic grad/Hessian partials (verified).
// ---------------------------------------------------------------------------
__global__ __launch_bounds__(256) void k_pair(
    const float* __restrict__ UA, const float* __restrict__ VAT,
    const float* __restrict__ UB, const float* __restrict__ VBT,
    const float* __restrict__ AW2, const float* __restrict__ AB2,
    const float* __restrict__ BW2, const float* __restrict__ BB2,
    const float* __restrict__ LP, const float* __restrict__ TP,
    const float* __restrict__ LVDW, const float* __restrict__ TVDW,
    const float* __restrict__ LNM, const float* __restrict__ TNM,
    const float* __restrict__ II, const float* __restrict__ HBC,
    const float* __restrict__ HPC, float* __restrict__ PART) {
  const int D = DC, N1 = N1C, N2 = N2C;
  int i = blockIdx.x, b = blockIdx.y, j = threadIdx.x;
  __shared__ float ua[128], ub[128], wa2[128], wb2[128];
  if (j < 128) {
    long rb = ((long)b * N1 + i) * D + j;
    ua[j] = UA[rb];
    ub[j] = UB[rb];
    wa2[j] = AW2[j];
    wb2[j] = BW2[j];
  }
  __syncthreads();
  const float* vat = VAT + (long)b * D * N2;
  const float* vbt = VBT + (long)b * D * N2;
  float dotA = 0.f, dotB = 0.f;
#pragma unroll 8
  for (int d = 0; d < D; ++d) {
    dotA += fmaxf(ua[d] + vat[(long)d * N2 + j], 0.f) * wa2[d];
    dotB += fmaxf(ub[d] + vbt[(long)d * N2 + j], 0.f) * wb2[d];
  }
  float A_raw = 1.f / (1.f + expf(-(dotA + AB2[0])));
  float A_vdw = A_raw * (0.0356f - 0.0178f) + 0.0178f;
  float B_raw = tanhf(dotB + BB2[0]) * 0.2f;

  float lx = LP[((long)b * N1 + i) * 3 + 0];
  float ly = LP[((long)b * N1 + i) * 3 + 1];
  float lz = LP[((long)b * N1 + i) * 3 + 2];
  float tx = TP[((long)b * N2 + j) * 3 + 0];
  float ty = TP[((long)b * N2 + j) * 3 + 1];
  float tz = TP[((long)b * N2 + j) * 3 + 2];
  float dx = lx - tx, dy = ly - ty, dz = lz - tz;
  float s2 = dx * dx + dy * dy + dz * dz + 1e-10f;
  float draw = sqrtf(s2);
  bool clamped = draw < 0.5f;
  float dmv = clamped ? 1e10f : draw;

  float dm0 = LVDW[b * N1 + i] + TVDW[b * N2 + j] + B_raw;
  float dm0c = (dm0 < 1e-4f) ? 1.f : dm0;
  float valid = LNM[b * N1 + i] * TNM[b * N2 + j];

  float rr = dm0c / dmv;
  float r2 = rr * rr, r6 = r2 * r2 * r2;
  float fv = r6 * r6 - 2.f * r6;
  float evdw = A_vdw * (fminf(fv, 100.f) * valid);

  float dmd = dmv - dm0;
  long ii0 = ((long)b * 3) * N1 * N2 + (long)i * N2 + j;
  float I0 = II[ii0];
  float I1 = II[ii0 + (long)N1 * N2];
  float I2 = II[ii0 + 2L * N1 * N2];
  float hb2 = HBC[0] * HBC[0], hp2 = HPC[0] * HPC[0];
  float u0 = dmd * I0 / (-0.7f);
  float u1 = dmd * I1 / (-0.7f);
  float vv = (1.5f - dmd) * I2;
  float ehb = fminf(fmaxf(u0, 0.f), 1.f) * (-hb2);
  float emt = fminf(fmaxf(u1, 0.f), 1.f) * (-hb2);
  float ehp = fminf(fmaxf(vv, 0.f), 1.f) * (-hp2);

  float gx = 0.f, gy = 0.f, gz = 0.f, d2t = 0.f;
  if (!clamped) {
    float Ep = 0.f, Epp = 0.f;
    if (fv < 100.f) {
      float c = A_vdw * valid;
      Ep += c * (-12.f) * r6 * (r6 - 1.f) / draw;
      Epp += c * r6 * (156.f * r6 - 84.f) / s2;
    }
    if (u0 > 0.f && u0 < 1.f) Ep += hb2 * I0 * (1.f / 0.7f);
    if (u1 > 0.f && u1 < 1.f) Ep += hb2 * I1 * (1.f / 0.7f);
    if (vv > 0.f && vv < 1.f) Ep += hp2 * I2;
    float invd = 1.f / draw;
    gx = Ep * dx * invd;
    gy = Ep * dy * invd;
    gz = Ep * dz * invd;
    float T = dx + dy + dz;
    float tt = T * T / s2;
    d2t = Epp * tt + Ep * (3.f - tt) * invd;
  }

  float o0 = blockSum(evdw);
  float o1 = blockSum(ehb);
  float o2 = blockSum(emt);
  float o3 = blockSum(ehp);
  float o4 = blockSum(gx);
  float o5 = blockSum(gy);
  float o6 = blockSum(gz);
  float o7 = blockSum(d2t);
  if (j == 0) {
    float* p = PART + ((long)b * N1 + i) * 8;
    p[0] = o0; p[1] = o1; p[2] = o2; p[3] = o3;
    p[4] = o4; p[5] = o5; p[6] = o6; p[7] = o7;
  }
}

// final deterministic reduction + output assembly (34 floats)
__global__ void k_final(const float* __restrict__ PART, const float* __restrict__ ROT,
                        const float* __restrict__ RC, float* __restrict__ OUT) {
  const int N1 = N1C;
  __shared__ float s[8][8];
  int t = threadIdx.x;
  if (t < 64) {
    int b = t >> 3, k1 = t & 7;
    float acc = 0.f;
    for (int i = 0; i < N1; ++i) acc += PART[((long)b * N1 + i) * 8 + k1];
    s[b][k1] = acc;
  }
  __syncthreads();
  if (t == 0) {
    float rcc = RC[0] * RC[0];
    float der1 = 0.f, der2 = 0.f;
    for (int b = 0; b < 8; ++b) {
      float w = 1.f / (1.f + rcc * ROT[b]);
      OUT[b * 4 + 0] = s[b][0] * w;
      OUT[b * 4 + 1] = s[b][1] * w;
      OUT[b * 4 + 2] = s[b][2] * w;
      OUT[b * 4 + 3] = s[b][3] * w;
      for (int c = 0; c < 3; ++c) {
        float S = s[b][4 + c] * w;
        der1 += S * S;
      }
      der2 += s[b][7] * w;
    }
    OUT[32] = der1 / 24.f;
    OUT[33] = -der2 / 8.f;
  }
}

// ---------------------------------------------------------------------------
// Host-side orchestration
// ---------------------------------------------------------------------------
extern "C" void kernel_launch(void* const* d_in, const int* in_sizes, int n_in,
                              void* d_out, int out_size, void* d_ws, size_t ws_size,
                              hipStream_t stream) {
  (void)in_sizes; (void)n_in; (void)out_size; (void)ws_size;
  const int D = DC;

  const float* ligand_h   = (const float*)d_in[0];
  const float* ligand_adj = (const float*)d_in[1];
  const float* target_h   = (const float*)d_in[2];
  const float* target_adj = (const float*)d_in[3];
  const float* inter_ind  = (const float*)d_in[4];
  const float* ligand_pos = (const float*)d_in[5];
  const float* target_pos = (const float*)d_in[6];
  const float* rotor      = (const float*)d_in[7];
  const float* lvdw       = (const float*)d_in[8];
  const float* tvdw       = (const float*)d_in[9];
  const float* lnm        = (const float*)d_in[12];
  const float* tnm        = (const float*)d_in[13];
  const float* emb_w      = (const float*)d_in[14];
  const float* gat_w      = (const float*)d_in[15];
  const float* gat_b      = (const float*)d_in[16];
  const float* gat_att    = (const float*)d_in[17];
  const float* gat_gate_w = (const float*)d_in[18];
  const float* gat_gate_b = (const float*)d_in[19];
  const float* int_wt_w   = (const float*)d_in[20];
  const float* int_wt_b   = (const float*)d_in[21];
  const float* int_mt_w   = (const float*)d_in[22];
  const float* int_mt_b   = (const float*)d_in[23];
  const float* gru_w_ih   = (const float*)d_in[24];
  const float* gru_w_hh   = (const float*)d_in[25];
  const float* gru_b_ih   = (const float*)d_in[26];
  const float* gru_b_hh   = (const float*)d_in[27];
  const float* A_w1       = (const float*)d_in[28];
  const float* A_b1       = (const float*)d_in[29];
  const float* A_w2       = (const float*)d_in[30];
  const float* A_b2       = (const float*)d_in[31];
  const float* B_w1       = (const float*)d_in[32];
  const float* B_b1       = (const float*)d_in[33];
  const float* B_w2       = (const float*)d_in[34];
  const float* B_b2       = (const float*)d_in[35];
  const float* hb_c       = (const float*)d_in[36];
  const float* hp_c       = (const float*)d_in[37];
  const float* rc_c       = (const float*)d_in[38];

  // workspace carve (floats)
  float* w = (float*)d_ws;
  auto take = [&](size_t n) { float* p = w; w += n; return p; };
  float* H0    = take((size_t)ROWS_ALL * DC);   // 393216
  float* H1    = take((size_t)ROWS_ALL * DC);
  float* NT    = take((size_t)ROWS_ALL * DC);
  float* E1    = take((size_t)ROWS_ALL * DC);
  float* EAL   = take((size_t)BB * N1C * N1C);  // 131072
  float* EAT   = take((size_t)BB * N2C * N2C);  // 524288
  float* ADJ12 = take((size_t)BB * N1C * N2C);  // 262144
  float* WA    = take((size_t)3 * DC * DC);     // 49152
  float* bA    = take((size_t)3 * DC);
  float* GIHT  = take((size_t)3 * DC * 384);    // 147456
  float* GHHT  = take((size_t)3 * DC * 384);
  float* PART  = take((size_t)BB * N1C * 8);
  // phase-disjoint aliases
  float* T1  = NT;
  float* M2  = E1;
  float* MSG = EAT;           // 393216 <= 524288
  float* UA  = EAL;           // 131072
  float* UB  = EAT;           // 131072 (front of EAT)
  float* VAT = NT;            // 262144 <= 393216
  float* VBT = E1;            // 262144

  // geometry adjacency + embedding + fused GAT weights
  k_adj12<<<(BB * N1C * N2C + 255) / 256, 256, 0, stream>>>(ligand_pos,
                                                            target_pos, ADJ12);
  k_emb<<<ROWS_ALL / 4, 128, 0, stream>>>(ligand_h, target_h, emb_w, H0);
  k_wfuse<<<dim3(33, 3), 128, 0, stream>>>(gat_w, gat_b, gat_att, WA, bA);

  float *cur = H0, *alt = H1;

  // GAT stack (3 layers)
  for (int l = 0; l < 3; ++l) {
    k_lin2h<<<ROWS_ALL / 4, 256, 0, stream>>>(
        cur, gat_w + (size_t)l * D * D, gat_b + l * D, WA + (size_t)l * D * D,
        bA + l * D, NT, E1, 1, 0);
    k_ea<N1C><<<dim3(N1C / 16, N1C / 16, BB), dim3(16, 16), 0, stream>>>(
        NT, E1, ligand_adj, EAL, 0);
    k_ea<N2C><<<dim3(N2C / 16, N2C / 16, BB), dim3(16, 16), 0, stream>>>(
        NT, E1, target_adj, EAT, ROWS_L);
    k_smagg<<<dim3(N2C / 8, BB, 2), 512, 0, stream>>>(
        EAL, EAT, NT, cur, gat_gate_w + l * 2 * D, gat_gate_b + l, alt);
    float* t = cur; cur = alt; alt = t;
  }

  // GRU weight transposes (single dispatch)
  k_tall<<<(6 * 49152 + 255) / 256, 256, 0, stream>>>(gru_w_ih, gru_w_hh, GIHT,
                                                      GHHT);

  // interaction layers (both directions per dispatch; both use OLD h)
  for (int l = 0; l < 3; ++l) {
    k_lin2h<<<ROWS_ALL / 4, 256, 0, stream>>>(
        cur, int_wt_w + (size_t)l * D * D, int_wt_b + l * D,
        int_mt_w + (size_t)l * D * D, int_mt_b + l * D, T1, M2, 1, 0);
    k_msg2z<<<dim3(N2C / 8, BB, 2), 256, 0, stream>>>(T1, M2, ADJ12, MSG);
    k_gruf<<<ROWS_ALL / 4, 384, 0, stream>>>(MSG, cur, GIHT + (size_t)l * D * 384,
                                             GHHT + (size_t)l * D * 384,
                                             gru_b_ih + l * 384,
                                             gru_b_hh + l * 384, alt);
    float* t = cur; cur = alt; alt = t;
  }

  // pairwise feature precompute (U normal layout, V transposed [b][d][j])
  k_lin2h<<<ROWS_L / 4, 256, 0, stream>>>(cur, A_w1, A_b1, B_w1, B_b1, UA, UB,
                                          1, 0);
  k_lin2h<<<ROWS_T / 4, 256, 0, stream>>>(cur + (size_t)ROWS_L * DC,
                                          A_w1 + D * D, nullptr, B_w1 + D * D,
                                          nullptr, VAT, VBT, N2C, 1);

  // pairwise physics + analytic derivatives
  k_pair<<<dim3(N1C, BB), 256, 0, stream>>>(UA, VAT, UB, VBT, A_w2, A_b2, B_w2,
                                            B_b2, ligand_pos, target_pos, lvdw,
                                            tvdw, lnm, tnm, inter_ind, hb_c,
                                            hp_c, PART);

  // final reduction -> 34 outputs
  k_final<<<1, 256, 0, stream>>>(PART, rotor, rc_c, (float*)d_out);
}